// Round 5
// baseline (1305.595 us; speedup 1.0000x reference)
//
#include <hip/hip_runtime.h>

#define DIM 64
#define TWO_DIM 128

__device__ __forceinline__ float fast_tanh(float x) {
  float cx = fminf(fmaxf(x, -15.0f), 15.0f);
  float e = __expf(2.0f * cx);
  return (e - 1.0f) / (e + 1.0f);
}

// histogram: cnt[idx[i]] += 1
__global__ void k_hist(const int* __restrict__ idx, int* __restrict__ cnt, int n) {
  int i = blockIdx.x * blockDim.x + threadIdx.x;
  if (i < n) atomicAdd(&cnt[idx[i]], 1);
}

// ---- 3-phase multi-block scan of deg[0..n) -> offs, cursor ----
__global__ void k_scan_part(const int* __restrict__ deg, int* __restrict__ bsum,
                            int n) {
  __shared__ int red[256];
  int t = threadIdx.x;
  int i = blockIdx.x * 256 + t;
  red[t] = (i < n) ? deg[i] : 0;
  __syncthreads();
#pragma unroll
  for (int off = 128; off >= 1; off >>= 1) {
    if (t < off) red[t] += red[t + off];
    __syncthreads();
  }
  if (t == 0) bsum[blockIdx.x] = red[0];
}

__global__ void k_scan_mid(int* __restrict__ bsum, int nb) {
  __shared__ int s[512];
  int t = threadIdx.x;
  int v = (t < nb) ? bsum[t] : 0;
  s[t] = v;
  __syncthreads();
#pragma unroll
  for (int off = 1; off < 512; off <<= 1) {
    int u = (t >= off) ? s[t - off] : 0;
    __syncthreads();
    s[t] += u;
    __syncthreads();
  }
  if (t < nb) bsum[t] = s[t] - v;  // exclusive
}

__global__ void k_scan_final(const int* __restrict__ deg, const int* __restrict__ bsum,
                             int* __restrict__ offs, int* __restrict__ cursor, int n) {
  __shared__ int s[256];
  int t = threadIdx.x;
  int i = blockIdx.x * 256 + t;
  int d = (i < n) ? deg[i] : 0;
  s[t] = d;
  __syncthreads();
#pragma unroll
  for (int off = 1; off < 256; off <<= 1) {
    int u = (t >= off) ? s[t - off] : 0;
    __syncthreads();
    s[t] += u;
    __syncthreads();
  }
  int ex = bsum[blockIdx.x] + s[t] - d;
  if (i < n) {
    offs[i] = ex;
    cursor[i] = ex;
  }
}

__global__ void k_scatter(const int* __restrict__ src, const int* __restrict__ dst,
                          int* __restrict__ cursor, int* __restrict__ csr, int E) {
  int e = blockIdx.x * blockDim.x + threadIdx.x;
  if (e < E) {
    int p = atomicAdd(&cursor[dst[e]], 1);
    csr[p] = src[e];
  }
}

// one 64-lane wave per node; lane = feature. agg[n][t] = sum over in-edges x[src][t]
__global__ void k_gather(const float* __restrict__ x, const int* __restrict__ csr,
                         const int* __restrict__ offs, const int* __restrict__ deg,
                         float* __restrict__ agg, int n) {
  int node = blockIdx.x * 4 + (threadIdx.x >> 6);
  int t = threadIdx.x & 63;
  if (node >= n) return;
  int s = offs[node], d = deg[node];
  float acc = 0.0f;
  for (int base = 0; base < d; base += 64) {
    int m = min(64, d - base);
    int myi = (t < m) ? csr[s + base + t] : 0;
    for (int i = 0; i < m; ++i) {
      int sn = __shfl(myi, i);
      acc += x[(size_t)sn * DIM + t];
    }
  }
  agg[(size_t)node * DIM + t] = acc;
}

// fold BN(eval) into scale/shift
__global__ void k_prep(const float* __restrict__ b1, const float* __restrict__ gamma,
                       const float* __restrict__ beta, float* __restrict__ sc,
                       float* __restrict__ sh) {
  int i = threadIdx.x;
  if (i < TWO_DIM) {
    float s = gamma[i] * rsqrtf(1.0f + 1e-5f);
    sc[i] = s;
    sh[i] = b1[i] * s + beta[i];
  }
}

// Layer-1 half of GIN MLP: hmid[m][j] = tanh(BN(sum_k v[m][k] * W1[k][j])).
// lane = hidden unit j (owns j and j+64); W1 columns held in 128 VGPRs,
// loaded once per wave and reused across ~n/waves nodes. v broadcast by shfl.
__launch_bounds__(256, 3)
__global__ void k_l1(const float* __restrict__ xin, const float* __restrict__ agg,
                     const float* __restrict__ epsp, const float* __restrict__ W1,
                     const float* __restrict__ sc, const float* __restrict__ sh,
                     float* __restrict__ hmid, int n) {
  const int lane = threadIdx.x & 63;
  float wa[DIM], wb[DIM];
#pragma unroll
  for (int k = 0; k < DIM; ++k) {
    wa[k] = W1[k * TWO_DIM + lane];
    wb[k] = W1[k * TWO_DIM + 64 + lane];
  }
  const float sca = sc[lane], scb = sc[lane + 64];
  const float sha = sh[lane], shb = sh[lane + 64];
  const float ep = 1.0f + epsp[0];
  const int gw = (blockIdx.x * blockDim.x + threadIdx.x) >> 6;
  const int nw = (gridDim.x * blockDim.x) >> 6;

  for (int m = gw; m < n; m += nw) {
    float v = ep * xin[(size_t)m * DIM + lane] + agg[(size_t)m * DIM + lane];
    float a0 = 0.f, a1 = 0.f, b0 = 0.f, b1 = 0.f;
#pragma unroll
    for (int k = 0; k < DIM; k += 2) {
      float v0 = __shfl(v, k);
      float v1 = __shfl(v, k + 1);
      a0 += v0 * wa[k];
      b0 += v0 * wb[k];
      a1 += v1 * wa[k + 1];
      b1 += v1 * wb[k + 1];
    }
    float hj = fast_tanh((a0 + a1) * sca + sha);
    float hj2 = fast_tanh((b0 + b1) * scb + shb);
    hmid[(size_t)m * TWO_DIM + lane] = hj;
    hmid[(size_t)m * TWO_DIM + 64 + lane] = hj2;
  }
}

// Layer-2 half: z[m][i] = tanh(sum_j hmid[m][j] * W2[j][i] + b2[i]).
// lane = output unit i; W2 column in 128 VGPRs. POOL: atomicAdd into pooled.
template <bool POOL>
__launch_bounds__(256, 3)
__global__ void k_l2(const float* __restrict__ hmid, const float* __restrict__ W2,
                     const float* __restrict__ b2, float* __restrict__ hout,
                     float* __restrict__ pooled, const int* __restrict__ batch,
                     int n) {
  const int lane = threadIdx.x & 63;
  float w[TWO_DIM];
#pragma unroll
  for (int j = 0; j < TWO_DIM; ++j) w[j] = W2[j * DIM + lane];
  const float bl = b2[lane];
  const int gw = (blockIdx.x * blockDim.x + threadIdx.x) >> 6;
  const int nw = (gridDim.x * blockDim.x) >> 6;

  for (int m = gw; m < n; m += nw) {
    float ha = hmid[(size_t)m * TWO_DIM + lane];
    float hb = hmid[(size_t)m * TWO_DIM + 64 + lane];
    float z0 = 0.f, z1 = 0.f, z2 = 0.f, z3 = 0.f;
#pragma unroll
    for (int j = 0; j < DIM; j += 2) {
      z0 += __shfl(ha, j) * w[j];
      z1 += __shfl(ha, j + 1) * w[j + 1];
      z2 += __shfl(hb, j) * w[64 + j];
      z3 += __shfl(hb, j + 1) * w[64 + j + 1];
    }
    float o = fast_tanh((z0 + z1) + (z2 + z3) + bl);
    if (POOL) {
      int b = batch[m];
      atomicAdd(&pooled[(size_t)b * DIM + lane], o);
    } else {
      hout[(size_t)m * DIM + lane] = o;
    }
  }
}

// out[g][i] = tanh( (pooled[g]/max(cnt,1)) . linW[:,i] + linb[i] )
__global__ void k_out(const float* __restrict__ pooled, const int* __restrict__ cnt,
                      const float* __restrict__ linW, const float* __restrict__ linb,
                      float* __restrict__ out) {
  int g = blockIdx.x;
  int i = threadIdx.x;
  int c = cnt[g];
  float inv = 1.0f / (float)(c > 0 ? c : 1);
  float acc = 0.0f;
#pragma unroll
  for (int k = 0; k < DIM; ++k)
    acc += pooled[(size_t)g * DIM + k] * linW[k * DIM + i];
  out[(size_t)g * DIM + i] = fast_tanh(acc * inv + linb[i]);
}

extern "C" void kernel_launch(void* const* d_in, const int* in_sizes, int n_in,
                              void* d_out, int out_size, void* d_ws, size_t ws_size,
                              hipStream_t stream) {
  const float* x = (const float*)d_in[0];
  const int* ei = (const int*)d_in[1];
  const int* batch = (const int*)d_in[2];
  const float* eps1 = (const float*)d_in[3];
  const float* W11 = (const float*)d_in[4];
  const float* b11 = (const float*)d_in[5];
  const float* g1 = (const float*)d_in[6];
  const float* be1 = (const float*)d_in[7];
  const float* W12 = (const float*)d_in[8];
  const float* b12 = (const float*)d_in[9];
  const float* eps2 = (const float*)d_in[10];
  const float* W21 = (const float*)d_in[11];
  const float* b21 = (const float*)d_in[12];
  const float* g2 = (const float*)d_in[13];
  const float* be2 = (const float*)d_in[14];
  const float* W22 = (const float*)d_in[15];
  const float* b22 = (const float*)d_in[16];
  const float* linW = (const float*)d_in[17];
  const float* linb = (const float*)d_in[18];

  const int n = in_sizes[0] / DIM;  // 100000
  const int E = in_sizes[1] / 2;    // 1600000
  const int G = out_size / DIM;     // 256
  const int* src = ei;
  const int* dst = ei + E;

  size_t off = 0;
  auto alloc = [&](size_t bytes) -> void* {
    void* p = (char*)d_ws + off;
    off += (bytes + 255) & ~(size_t)255;
    return p;
  };
  float* agg = (float*)alloc((size_t)n * DIM * 4);
  float* h1 = (float*)alloc((size_t)n * DIM * 4);
  float* hmid = (float*)alloc((size_t)n * TWO_DIM * 4);
  int* deg = (int*)alloc((size_t)n * 4);
  int* offs = (int*)alloc((size_t)n * 4);
  int* cursor = (int*)alloc((size_t)n * 4);
  int* csr = (int*)alloc((size_t)E * 4);
  float* sc1 = (float*)alloc(TWO_DIM * 4);
  float* sh1 = (float*)alloc(TWO_DIM * 4);
  float* sc2 = (float*)alloc(TWO_DIM * 4);
  float* sh2 = (float*)alloc(TWO_DIM * 4);
  float* pooled = (float*)alloc((size_t)G * DIM * 4);
  int* cnt = (int*)alloc((size_t)G * 4);
  int* bsum = (int*)alloc(512 * 4);

  hipMemsetAsync(deg, 0, (size_t)n * 4, stream);
  hipMemsetAsync(cnt, 0, (size_t)G * 4, stream);
  hipMemsetAsync(pooled, 0, (size_t)G * DIM * 4, stream);

  const int nb = (n + 255) / 256;  // 391
  k_hist<<<(E + 255) / 256, 256, 0, stream>>>(dst, deg, E);
  k_hist<<<(n + 255) / 256, 256, 0, stream>>>(batch, cnt, n);
  k_scan_part<<<nb, 256, 0, stream>>>(deg, bsum, n);
  k_scan_mid<<<1, 512, 0, stream>>>(bsum, nb);
  k_scan_final<<<nb, 256, 0, stream>>>(deg, bsum, offs, cursor, n);
  k_scatter<<<(E + 255) / 256, 256, 0, stream>>>(src, dst, cursor, csr, E);
  k_prep<<<1, TWO_DIM, 0, stream>>>(b11, g1, be1, sc1, sh1);
  k_prep<<<1, TWO_DIM, 0, stream>>>(b21, g2, be2, sc2, sh2);

  const int MLP_BLOCKS = 768;  // 3072 waves = 12 waves/CU at 3/SIMD
  k_gather<<<(n + 3) / 4, 256, 0, stream>>>(x, csr, offs, deg, agg, n);
  k_l1<<<MLP_BLOCKS, 256, 0, stream>>>(x, agg, eps1, W11, sc1, sh1, hmid, n);
  k_l2<false><<<MLP_BLOCKS, 256, 0, stream>>>(hmid, W12, b12, h1, nullptr, nullptr,
                                              n);
  k_gather<<<(n + 3) / 4, 256, 0, stream>>>(h1, csr, offs, deg, agg, n);
  k_l1<<<MLP_BLOCKS, 256, 0, stream>>>(h1, agg, eps2, W21, sc2, sh2, hmid, n);
  k_l2<true><<<MLP_BLOCKS, 256, 0, stream>>>(hmid, W22, b22, nullptr, pooled, batch,
                                             n);
  k_out<<<G, DIM, 0, stream>>>(pooled, cnt, linW, linb, (float*)d_out);
}

// Round 6
// 686.283 us; speedup vs baseline: 1.9024x; 1.9024x over previous
//
#include <hip/hip_runtime.h>

#define DIM 64
#define TWO_DIM 128

typedef __attribute__((ext_vector_type(8))) short bf16x8;
typedef __attribute__((ext_vector_type(4))) float f32x4;
#define MFMA16(A, B, C) __builtin_amdgcn_mfma_f32_16x16x32_bf16(A, B, C, 0, 0, 0)

__device__ __forceinline__ float fast_tanh(float x) {
  float cx = fminf(fmaxf(x, -15.0f), 15.0f);
  float e = __expf(2.0f * cx);
  return (e - 1.0f) / (e + 1.0f);
}

__device__ __forceinline__ unsigned short f2bf(float x) {
  unsigned int b = __float_as_uint(x);
  unsigned int r = b + 0x7FFFu + ((b >> 16) & 1u);
  return (unsigned short)(r >> 16);
}
__device__ __forceinline__ float bf2f(unsigned short h) {
  return __uint_as_float(((unsigned int)h) << 16);
}
__device__ __forceinline__ uint4 pack8(const unsigned short* s) {
  uint4 u;
  u.x = (unsigned)s[0] | ((unsigned)s[1] << 16);
  u.y = (unsigned)s[2] | ((unsigned)s[3] << 16);
  u.z = (unsigned)s[4] | ((unsigned)s[5] << 16);
  u.w = (unsigned)s[6] | ((unsigned)s[7] << 16);
  return u;
}

// ---------------- graph machinery ----------------
__global__ void k_hist(const int* __restrict__ idx, int* __restrict__ cnt, int n) {
  int i = blockIdx.x * blockDim.x + threadIdx.x;
  if (i < n) atomicAdd(&cnt[idx[i]], 1);
}

__global__ void k_scan_part(const int* __restrict__ deg, int* __restrict__ bsum,
                            int n) {
  __shared__ int red[256];
  int t = threadIdx.x;
  int i = blockIdx.x * 256 + t;
  red[t] = (i < n) ? deg[i] : 0;
  __syncthreads();
#pragma unroll
  for (int off = 128; off >= 1; off >>= 1) {
    if (t < off) red[t] += red[t + off];
    __syncthreads();
  }
  if (t == 0) bsum[blockIdx.x] = red[0];
}

__global__ void k_scan_mid(int* __restrict__ bsum, int nb) {
  __shared__ int s[512];
  int t = threadIdx.x;
  int v = (t < nb) ? bsum[t] : 0;
  s[t] = v;
  __syncthreads();
#pragma unroll
  for (int off = 1; off < 512; off <<= 1) {
    int u = (t >= off) ? s[t - off] : 0;
    __syncthreads();
    s[t] += u;
    __syncthreads();
  }
  if (t < nb) bsum[t] = s[t] - v;
}

__global__ void k_scan_final(const int* __restrict__ deg, const int* __restrict__ bsum,
                             int* __restrict__ offs, int* __restrict__ cursor, int n) {
  __shared__ int s[256];
  int t = threadIdx.x;
  int i = blockIdx.x * 256 + t;
  int d = (i < n) ? deg[i] : 0;
  s[t] = d;
  __syncthreads();
#pragma unroll
  for (int off = 1; off < 256; off <<= 1) {
    int u = (t >= off) ? s[t - off] : 0;
    __syncthreads();
    s[t] += u;
    __syncthreads();
  }
  int ex = bsum[blockIdx.x] + s[t] - d;
  if (i < n) {
    offs[i] = ex;
    cursor[i] = ex;
  }
}

__global__ void k_scatter(const int* __restrict__ src, const int* __restrict__ dst,
                          int* __restrict__ cursor, int* __restrict__ csr, int E) {
  int e = blockIdx.x * blockDim.x + threadIdx.x;
  if (e < E) {
    int p = atomicAdd(&cursor[dst[e]], 1);
    csr[p] = src[e];
  }
}

// one 64-lane wave per node; lane = feature
__global__ void k_gather(const float* __restrict__ x, const int* __restrict__ csr,
                         const int* __restrict__ offs, const int* __restrict__ deg,
                         float* __restrict__ agg, int n) {
  int node = blockIdx.x * 4 + (threadIdx.x >> 6);
  int t = threadIdx.x & 63;
  if (node >= n) return;
  int s = offs[node], d = deg[node];
  float acc = 0.0f;
  for (int base = 0; base < d; base += 64) {
    int m = min(64, d - base);
    int myi = (t < m) ? csr[s + base + t] : 0;
    for (int i = 0; i < m; ++i) {
      int sn = __shfl(myi, i);
      acc += x[(size_t)sn * DIM + t];
    }
  }
  agg[(size_t)node * DIM + t] = acc;
}

// fold BN(eval) into scale/shift
__global__ void k_prep(const float* __restrict__ b1, const float* __restrict__ gamma,
                       const float* __restrict__ beta, float* __restrict__ sc,
                       float* __restrict__ sh) {
  int i = threadIdx.x;
  if (i < TWO_DIM) {
    float s = gamma[i] * rsqrtf(1.0f + 1e-5f);
    sc[i] = s;
    sh[i] = b1[i] * s + beta[i];
  }
}

// Pack W1 [64][128] and W2 [128][64] into MFMA B-fragment order, hi/lo bf16 split.
// B-frag: lane l holds B[k = f*32 + 8*(l>>4) + e][n = nt*16 + (l&15)], e=0..7.
// W1p: idx (nt*2+f)*64+lane (nt<8,f<2); W2p: idx (nt*4+f)*64+lane (nt<4,f<4).
__global__ void k_prepw(const float* __restrict__ W1, const float* __restrict__ W2,
                        uint4* __restrict__ w1h, uint4* __restrict__ w1l,
                        uint4* __restrict__ w2h, uint4* __restrict__ w2l) {
  int p = blockIdx.x * 256 + threadIdx.x;  // 0..2047
  if (p >= 2048) return;
  int lane = p & 63;
  int c = lane & 15, g = lane >> 4;
  unsigned short hh[8], ll[8];
  if (p < 1024) {
    int nt = p >> 7, f = (p >> 6) & 1;
    int nn = nt * 16 + c, kb = f * 32 + g * 8;
#pragma unroll
    for (int e = 0; e < 8; ++e) {
      float w = W1[(kb + e) * TWO_DIM + nn];
      hh[e] = f2bf(w);
      ll[e] = f2bf(w - bf2f(hh[e]));
    }
    w1h[p] = pack8(hh);
    w1l[p] = pack8(ll);
  } else {
    int q = p - 1024;
    int nt = q >> 8, f = (q >> 6) & 3;
    int nn = nt * 16 + c, kb = f * 32 + g * 8;
#pragma unroll
    for (int e = 0; e < 8; ++e) {
      float w = W2[(kb + e) * DIM + nn];
      hh[e] = f2bf(w);
      ll[e] = f2bf(w - bf2f(hh[e]));
    }
    w2h[q] = pack8(hh);
    w2l[q] = pack8(ll);
  }
}

// v = (1+eps)*x + agg, split hi/lo bf16, packed in MFMA A-frag order:
// A-frag: lane l holds A[m = T*16 + (l&15)][k = f*32 + 8*(l>>4) + e].
// vh/vl idx = (T*2+f)*64 + lane.
__global__ void k_split(const float* __restrict__ xin, const float* __restrict__ agg,
                        const float* __restrict__ epsp, uint4* __restrict__ vh,
                        uint4* __restrict__ vl, int n, int P) {
  int p = blockIdx.x * 256 + threadIdx.x;
  if (p >= P) return;
  float ep = 1.0f + epsp[0];
  int lane = p & 63;
  int T = p >> 7;
  int f = (p >> 6) & 1;
  int m = T * 16 + (lane & 15);
  int k0 = f * 32 + (lane >> 4) * 8;
  float v[8];
  if (m < n) {
    const float4* xa = reinterpret_cast<const float4*>(xin + (size_t)m * DIM + k0);
    const float4* aa = reinterpret_cast<const float4*>(agg + (size_t)m * DIM + k0);
    float4 x0 = xa[0], x1 = xa[1], a0 = aa[0], a1 = aa[1];
    v[0] = ep * x0.x + a0.x; v[1] = ep * x0.y + a0.y;
    v[2] = ep * x0.z + a0.z; v[3] = ep * x0.w + a0.w;
    v[4] = ep * x1.x + a1.x; v[5] = ep * x1.y + a1.y;
    v[6] = ep * x1.z + a1.z; v[7] = ep * x1.w + a1.w;
  } else {
#pragma unroll
    for (int e = 0; e < 8; ++e) v[e] = 0.0f;
  }
  unsigned short hh[8], ll[8];
#pragma unroll
  for (int e = 0; e < 8; ++e) {
    hh[e] = f2bf(v[e]);
    ll[e] = f2bf(v[e] - bf2f(hh[e]));
  }
  vh[p] = pack8(hh);
  vl[p] = pack8(ll);
}

// GEMM1 + BN + tanh + split + repack for GEMM2.
// Block = 4 waves, wave = one 16-node m-tile. C = V[16x64] @ W1[64x128].
__launch_bounds__(256, 2)
__global__ void k_g1(const uint4* __restrict__ vh, const uint4* __restrict__ vl,
                     const uint4* __restrict__ w1h, const uint4* __restrict__ w1l,
                     const float* __restrict__ sc, const float* __restrict__ sh,
                     uint4* __restrict__ hh, uint4* __restrict__ hl, int NTiles) {
  __shared__ uint4 sBh[1024], sBl[1024];      // 16 KB + 16 KB
  __shared__ float ssc[TWO_DIM], ssh[TWO_DIM];
  __shared__ float sH[4 * 16 * 132];          // 33.8 KB, per-wave 16x132 tile

  int t = threadIdx.x;
#pragma unroll
  for (int q = 0; q < 4; ++q) {
    sBh[q * 256 + t] = w1h[q * 256 + t];
    sBl[q * 256 + t] = w1l[q * 256 + t];
  }
  if (t < TWO_DIM) {
    ssc[t] = sc[t];
    ssh[t] = sh[t];
  }
  __syncthreads();

  const int wid = t >> 6, lane = t & 63;
  const int T = blockIdx.x * 4 + wid;
  if (T >= NTiles) return;
  const int c = lane & 15, g = lane >> 4;

  const bf16x8* Ah = reinterpret_cast<const bf16x8*>(vh + (size_t)T * 128);
  const bf16x8* Al = reinterpret_cast<const bf16x8*>(vl + (size_t)T * 128);
  bf16x8 ah0 = Ah[lane], ah1 = Ah[64 + lane];
  bf16x8 al0 = Al[lane], al1 = Al[64 + lane];

  const bf16x8* Bh = reinterpret_cast<const bf16x8*>(sBh);
  const bf16x8* Bl = reinterpret_cast<const bf16x8*>(sBl);
  float* myH = sH + wid * (16 * 132);

#pragma unroll
  for (int nt = 0; nt < 8; ++nt) {
    f32x4 acc = {0.f, 0.f, 0.f, 0.f};
    bf16x8 bh0 = Bh[(nt * 2 + 0) * 64 + lane];
    bf16x8 bl0 = Bl[(nt * 2 + 0) * 64 + lane];
    bf16x8 bh1 = Bh[(nt * 2 + 1) * 64 + lane];
    bf16x8 bl1 = Bl[(nt * 2 + 1) * 64 + lane];
    acc = MFMA16(ah0, bh0, acc);
    acc = MFMA16(ah1, bh1, acc);
    acc = MFMA16(ah0, bl0, acc);
    acc = MFMA16(ah1, bl1, acc);
    acc = MFMA16(al0, bh0, acc);
    acc = MFMA16(al1, bh1, acc);
    int j = nt * 16 + c;
    float scj = ssc[j], shj = ssh[j];
#pragma unroll
    for (int r = 0; r < 4; ++r)
      myH[(g * 4 + r) * 132 + j] = fast_tanh(acc[r] * scj + shj);
  }

  // repack rows of myH into GEMM2 A-frag order (hi/lo split)
#pragma unroll
  for (int f2 = 0; f2 < 4; ++f2) {
    const float* hp = myH + c * 132 + f2 * 32 + g * 8;
    float4 v0 = *reinterpret_cast<const float4*>(hp);
    float4 v1 = *reinterpret_cast<const float4*>(hp + 4);
    float vv[8] = {v0.x, v0.y, v0.z, v0.w, v1.x, v1.y, v1.z, v1.w};
    unsigned short H[8], L[8];
#pragma unroll
    for (int e = 0; e < 8; ++e) {
      H[e] = f2bf(vv[e]);
      L[e] = f2bf(vv[e] - bf2f(H[e]));
    }
    size_t o = ((size_t)T * 4 + f2) * 64 + lane;
    hh[o] = pack8(H);
    hl[o] = pack8(L);
  }
}

// GEMM2 + tanh (+pool). C = H[16x128] @ W2[128x64].
template <bool POOL>
__launch_bounds__(256, 2)
__global__ void k_g2(const uint4* __restrict__ hh, const uint4* __restrict__ hl,
                     const uint4* __restrict__ w2h, const uint4* __restrict__ w2l,
                     const float* __restrict__ b2, float* __restrict__ hout,
                     float* __restrict__ pooled, const int* __restrict__ batch,
                     int n, int NTiles) {
  __shared__ uint4 sBh[1024], sBl[1024];
  __shared__ float sb2[DIM];

  int t = threadIdx.x;
#pragma unroll
  for (int q = 0; q < 4; ++q) {
    sBh[q * 256 + t] = w2h[q * 256 + t];
    sBl[q * 256 + t] = w2l[q * 256 + t];
  }
  if (t < DIM) sb2[t] = b2[t];
  __syncthreads();

  const int wid = t >> 6, lane = t & 63;
  const int T = blockIdx.x * 4 + wid;
  if (T >= NTiles) return;
  const int c = lane & 15, g = lane >> 4;

  const bf16x8* Ah = reinterpret_cast<const bf16x8*>(hh + (size_t)T * 256);
  const bf16x8* Al = reinterpret_cast<const bf16x8*>(hl + (size_t)T * 256);
  bf16x8 ah0 = Ah[lane], ah1 = Ah[64 + lane], ah2 = Ah[128 + lane], ah3 = Ah[192 + lane];
  bf16x8 al0 = Al[lane], al1 = Al[64 + lane], al2 = Al[128 + lane], al3 = Al[192 + lane];

  const bf16x8* Bh = reinterpret_cast<const bf16x8*>(sBh);
  const bf16x8* Bl = reinterpret_cast<const bf16x8*>(sBl);

  bool uni = false;
  int b0 = 0;
  if (POOL) {
    b0 = batch[min(T * 16, n - 1)];
    int b15 = batch[min(T * 16 + 15, n - 1)];
    uni = (b0 == b15) && (T * 16 + 15 < n);
  }

#pragma unroll
  for (int nt = 0; nt < 4; ++nt) {
    f32x4 acc = {0.f, 0.f, 0.f, 0.f};
    bf16x8 bh0 = Bh[(nt * 4 + 0) * 64 + lane];
    bf16x8 bh1 = Bh[(nt * 4 + 1) * 64 + lane];
    bf16x8 bh2 = Bh[(nt * 4 + 2) * 64 + lane];
    bf16x8 bh3 = Bh[(nt * 4 + 3) * 64 + lane];
    bf16x8 bl0 = Bl[(nt * 4 + 0) * 64 + lane];
    bf16x8 bl1 = Bl[(nt * 4 + 1) * 64 + lane];
    bf16x8 bl2 = Bl[(nt * 4 + 2) * 64 + lane];
    bf16x8 bl3 = Bl[(nt * 4 + 3) * 64 + lane];
    acc = MFMA16(ah0, bh0, acc);
    acc = MFMA16(ah1, bh1, acc);
    acc = MFMA16(ah2, bh2, acc);
    acc = MFMA16(ah3, bh3, acc);
    acc = MFMA16(ah0, bl0, acc);
    acc = MFMA16(ah1, bl1, acc);
    acc = MFMA16(ah2, bl2, acc);
    acc = MFMA16(ah3, bl3, acc);
    acc = MFMA16(al0, bh0, acc);
    acc = MFMA16(al1, bh1, acc);
    acc = MFMA16(al2, bh2, acc);
    acc = MFMA16(al3, bh3, acc);

    int j = nt * 16 + c;
    float bj = sb2[j];
    float o0 = fast_tanh(acc[0] + bj);
    float o1 = fast_tanh(acc[1] + bj);
    float o2 = fast_tanh(acc[2] + bj);
    float o3 = fast_tanh(acc[3] + bj);
    if (POOL) {
      if (uni) {
        float os = (o0 + o1) + (o2 + o3);
        os += __shfl_xor(os, 16);
        os += __shfl_xor(os, 32);
        if (g == 0) atomicAdd(&pooled[(size_t)b0 * DIM + j], os);
      } else {
        int mb = T * 16 + g * 4;
#pragma unroll
        for (int r = 0; r < 4; ++r) {
          int m = mb + r;
          float o = (r == 0) ? o0 : (r == 1) ? o1 : (r == 2) ? o2 : o3;
          if (m < n) atomicAdd(&pooled[(size_t)batch[m] * DIM + j], o);
        }
      }
    } else {
      int mb = T * 16 + g * 4;
      if (mb + 0 < n) hout[(size_t)(mb + 0) * DIM + j] = o0;
      if (mb + 1 < n) hout[(size_t)(mb + 1) * DIM + j] = o1;
      if (mb + 2 < n) hout[(size_t)(mb + 2) * DIM + j] = o2;
      if (mb + 3 < n) hout[(size_t)(mb + 3) * DIM + j] = o3;
    }
  }
}

// out[g][i] = tanh( (pooled[g]/max(cnt,1)) . linW[:,i] + linb[i] )
__global__ void k_out(const float* __restrict__ pooled, const int* __restrict__ cnt,
                      const float* __restrict__ linW, const float* __restrict__ linb,
                      float* __restrict__ out) {
  int g = blockIdx.x;
  int i = threadIdx.x;
  int c = cnt[g];
  float inv = 1.0f / (float)(c > 0 ? c : 1);
  float acc = 0.0f;
#pragma unroll
  for (int k = 0; k < DIM; ++k)
    acc += pooled[(size_t)g * DIM + k] * linW[k * DIM + i];
  out[(size_t)g * DIM + i] = fast_tanh(acc * inv + linb[i]);
}

extern "C" void kernel_launch(void* const* d_in, const int* in_sizes, int n_in,
                              void* d_out, int out_size, void* d_ws, size_t ws_size,
                              hipStream_t stream) {
  const float* x = (const float*)d_in[0];
  const int* ei = (const int*)d_in[1];
  const int* batch = (const int*)d_in[2];
  const float* eps1 = (const float*)d_in[3];
  const float* W11 = (const float*)d_in[4];
  const float* b11 = (const float*)d_in[5];
  const float* g1 = (const float*)d_in[6];
  const float* be1 = (const float*)d_in[7];
  const float* W12 = (const float*)d_in[8];
  const float* b12 = (const float*)d_in[9];
  const float* eps2 = (const float*)d_in[10];
  const float* W21 = (const float*)d_in[11];
  const float* b21 = (const float*)d_in[12];
  const float* g2 = (const float*)d_in[13];
  const float* be2 = (const float*)d_in[14];
  const float* W22 = (const float*)d_in[15];
  const float* b22 = (const float*)d_in[16];
  const float* linW = (const float*)d_in[17];
  const float* linb = (const float*)d_in[18];

  const int n = in_sizes[0] / DIM;  // 100000
  const int E = in_sizes[1] / 2;    // 1600000
  const int G = out_size / DIM;     // 256
  const int* src = ei;
  const int* dst = ei + E;
  const int NT = (n + 15) / 16;     // 6250
  const int P = NT * 128;           // packed uint4 count for V

  size_t off = 0;
  auto alloc = [&](size_t bytes) -> void* {
    void* p = (char*)d_ws + off;
    off += (bytes + 255) & ~(size_t)255;
    return p;
  };
  float* agg = (float*)alloc((size_t)n * DIM * 4);
  float* h1 = (float*)alloc((size_t)n * DIM * 4);
  uint4* vhi = (uint4*)alloc((size_t)P * 16);
  uint4* vlo = (uint4*)alloc((size_t)P * 16);
  uint4* hhi = (uint4*)alloc((size_t)NT * 256 * 16);
  uint4* hlo = (uint4*)alloc((size_t)NT * 256 * 16);
  int* deg = (int*)alloc((size_t)n * 4);
  int* offs = (int*)alloc((size_t)n * 4);
  int* cursor = (int*)alloc((size_t)n * 4);
  int* csr = (int*)alloc((size_t)E * 4);
  float* sc1 = (float*)alloc(TWO_DIM * 4);
  float* sh1 = (float*)alloc(TWO_DIM * 4);
  float* sc2 = (float*)alloc(TWO_DIM * 4);
  float* sh2 = (float*)alloc(TWO_DIM * 4);
  uint4* w1hA = (uint4*)alloc(1024 * 16);
  uint4* w1lA = (uint4*)alloc(1024 * 16);
  uint4* w2hA = (uint4*)alloc(1024 * 16);
  uint4* w2lA = (uint4*)alloc(1024 * 16);
  uint4* w1hB = (uint4*)alloc(1024 * 16);
  uint4* w1lB = (uint4*)alloc(1024 * 16);
  uint4* w2hB = (uint4*)alloc(1024 * 16);
  uint4* w2lB = (uint4*)alloc(1024 * 16);
  float* pooled = (float*)alloc((size_t)G * DIM * 4);
  int* cnt = (int*)alloc((size_t)G * 4);
  int* bsum = (int*)alloc(512 * 4);

  hipMemsetAsync(deg, 0, (size_t)n * 4, stream);
  hipMemsetAsync(cnt, 0, (size_t)G * 4, stream);
  hipMemsetAsync(pooled, 0, (size_t)G * DIM * 4, stream);

  const int nb = (n + 255) / 256;
  k_hist<<<(E + 255) / 256, 256, 0, stream>>>(dst, deg, E);
  k_hist<<<(n + 255) / 256, 256, 0, stream>>>(batch, cnt, n);
  k_scan_part<<<nb, 256, 0, stream>>>(deg, bsum, n);
  k_scan_mid<<<1, 512, 0, stream>>>(bsum, nb);
  k_scan_final<<<nb, 256, 0, stream>>>(deg, bsum, offs, cursor, n);
  k_scatter<<<(E + 255) / 256, 256, 0, stream>>>(src, dst, cursor, csr, E);
  k_prep<<<1, TWO_DIM, 0, stream>>>(b11, g1, be1, sc1, sh1);
  k_prep<<<1, TWO_DIM, 0, stream>>>(b21, g2, be2, sc2, sh2);
  k_prepw<<<8, 256, 0, stream>>>(W11, W12, w1hA, w1lA, w2hA, w2lA);
  k_prepw<<<8, 256, 0, stream>>>(W21, W22, w1hB, w1lB, w2hB, w2lB);

  const int gT = (NT + 3) / 4;  // 1563
  // GIN layer 1
  k_gather<<<(n + 3) / 4, 256, 0, stream>>>(x, csr, offs, deg, agg, n);
  k_split<<<(P + 255) / 256, 256, 0, stream>>>(x, agg, eps1, vhi, vlo, n, P);
  k_g1<<<gT, 256, 0, stream>>>(vhi, vlo, w1hA, w1lA, sc1, sh1, hhi, hlo, NT);
  k_g2<false><<<gT, 256, 0, stream>>>(hhi, hlo, w2hA, w2lA, b12, h1, nullptr,
                                      nullptr, n, NT);
  // GIN layer 2
  k_gather<<<(n + 3) / 4, 256, 0, stream>>>(h1, csr, offs, deg, agg, n);
  k_split<<<(P + 255) / 256, 256, 0, stream>>>(h1, agg, eps2, vhi, vlo, n, P);
  k_g1<<<gT, 256, 0, stream>>>(vhi, vlo, w1hB, w1lB, sc2, sh2, hhi, hlo, NT);
  k_g2<true><<<gT, 256, 0, stream>>>(hhi, hlo, w2hB, w2lB, b22, nullptr, pooled,
                                     batch, n, NT);
  k_out<<<G, DIM, 0, stream>>>(pooled, cnt, linW, linb, (float*)d_out);
}

// Round 7
// 647.410 us; speedup vs baseline: 2.0166x; 1.0600x over previous
//
#include <hip/hip_runtime.h>

#define DIM 64
#define TWO_DIM 128

typedef __attribute__((ext_vector_type(8))) short bf16x8;
typedef __attribute__((ext_vector_type(4))) float f32x4;
#define MFMA16(A, B, C) __builtin_amdgcn_mfma_f32_16x16x32_bf16(A, B, C, 0, 0, 0)

__device__ __forceinline__ float fast_tanh(float x) {
  float cx = fminf(fmaxf(x, -15.0f), 15.0f);
  float e = __expf(2.0f * cx);
  return (e - 1.0f) / (e + 1.0f);
}

__device__ __forceinline__ unsigned short f2bf(float x) {
  unsigned int b = __float_as_uint(x);
  unsigned int r = b + 0x7FFFu + ((b >> 16) & 1u);
  return (unsigned short)(r >> 16);
}
__device__ __forceinline__ float bf2f(unsigned short h) {
  return __uint_as_float(((unsigned int)h) << 16);
}
__device__ __forceinline__ uint4 pack8(const unsigned short* s) {
  uint4 u;
  u.x = (unsigned)s[0] | ((unsigned)s[1] << 16);
  u.y = (unsigned)s[2] | ((unsigned)s[3] << 16);
  u.z = (unsigned)s[4] | ((unsigned)s[5] << 16);
  u.w = (unsigned)s[6] | ((unsigned)s[7] << 16);
  return u;
}

// ---------------- graph machinery ----------------
// grid-stride histogram, int4 loads, 4 atomics in flight per iter
__global__ void k_hist(const int* __restrict__ idx, int* __restrict__ cnt, int n) {
  int tid = blockIdx.x * blockDim.x + threadIdx.x;
  int stride = gridDim.x * blockDim.x;
  int n4 = n >> 2;
  const int4* p = reinterpret_cast<const int4*>(idx);
  for (int i = tid; i < n4; i += stride) {
    int4 v = p[i];
    atomicAdd(&cnt[v.x], 1);
    atomicAdd(&cnt[v.y], 1);
    atomicAdd(&cnt[v.z], 1);
    atomicAdd(&cnt[v.w], 1);
  }
  if (tid == 0) {
    for (int i = n4 << 2; i < n; ++i) atomicAdd(&cnt[idx[i]], 1);
  }
}

__global__ void k_scan_part(const int* __restrict__ deg, int* __restrict__ bsum,
                            int n) {
  __shared__ int red[256];
  int t = threadIdx.x;
  int i = blockIdx.x * 256 + t;
  red[t] = (i < n) ? deg[i] : 0;
  __syncthreads();
#pragma unroll
  for (int off = 128; off >= 1; off >>= 1) {
    if (t < off) red[t] += red[t + off];
    __syncthreads();
  }
  if (t == 0) bsum[blockIdx.x] = red[0];
}

__global__ void k_scan_mid(int* __restrict__ bsum, int nb) {
  __shared__ int s[512];
  int t = threadIdx.x;
  int v = (t < nb) ? bsum[t] : 0;
  s[t] = v;
  __syncthreads();
#pragma unroll
  for (int off = 1; off < 512; off <<= 1) {
    int u = (t >= off) ? s[t - off] : 0;
    __syncthreads();
    s[t] += u;
    __syncthreads();
  }
  if (t < nb) bsum[t] = s[t] - v;
}

__global__ void k_scan_final(const int* __restrict__ deg, const int* __restrict__ bsum,
                             int* __restrict__ offs, int* __restrict__ cursor, int n) {
  __shared__ int s[256];
  int t = threadIdx.x;
  int i = blockIdx.x * 256 + t;
  int d = (i < n) ? deg[i] : 0;
  s[t] = d;
  __syncthreads();
#pragma unroll
  for (int off = 1; off < 256; off <<= 1) {
    int u = (t >= off) ? s[t - off] : 0;
    __syncthreads();
    s[t] += u;
    __syncthreads();
  }
  int ex = bsum[blockIdx.x] + s[t] - d;
  if (i < n) {
    offs[i] = ex;
    cursor[i] = ex;
  }
}

// grid-stride scatter, int4 loads, 4 independent atomic+store chains per iter
__global__ void k_scatter(const int* __restrict__ src, const int* __restrict__ dst,
                          int* __restrict__ cursor, int* __restrict__ csr, int E) {
  int tid = blockIdx.x * blockDim.x + threadIdx.x;
  int stride = gridDim.x * blockDim.x;
  int E4 = E >> 2;
  const int4* s4 = reinterpret_cast<const int4*>(src);
  const int4* d4 = reinterpret_cast<const int4*>(dst);
  for (int i = tid; i < E4; i += stride) {
    int4 s = s4[i];
    int4 d = d4[i];
    int p0 = atomicAdd(&cursor[d.x], 1);
    int p1 = atomicAdd(&cursor[d.y], 1);
    int p2 = atomicAdd(&cursor[d.z], 1);
    int p3 = atomicAdd(&cursor[d.w], 1);
    csr[p0] = s.x;
    csr[p1] = s.y;
    csr[p2] = s.z;
    csr[p3] = s.w;
  }
  if (tid == 0) {
    for (int i = E4 << 2; i < E; ++i) {
      int p = atomicAdd(&cursor[dst[i]], 1);
      csr[p] = src[i];
    }
  }
}

// one 64-lane wave per node; lane = feature
__global__ void k_gather(const float* __restrict__ x, const int* __restrict__ csr,
                         const int* __restrict__ offs, const int* __restrict__ deg,
                         float* __restrict__ agg, int n) {
  int node = blockIdx.x * 4 + (threadIdx.x >> 6);
  int t = threadIdx.x & 63;
  if (node >= n) return;
  int s = offs[node], d = deg[node];
  float acc = 0.0f;
  for (int base = 0; base < d; base += 64) {
    int m = min(64, d - base);
    int myi = (t < m) ? csr[s + base + t] : 0;
    for (int i = 0; i < m; ++i) {
      int sn = __shfl(myi, i);
      acc += x[(size_t)sn * DIM + t];
    }
  }
  agg[(size_t)node * DIM + t] = acc;
}

// fold BN(eval) into scale/shift
__global__ void k_prep(const float* __restrict__ b1, const float* __restrict__ gamma,
                       const float* __restrict__ beta, float* __restrict__ sc,
                       float* __restrict__ sh) {
  int i = threadIdx.x;
  if (i < TWO_DIM) {
    float s = gamma[i] * rsqrtf(1.0f + 1e-5f);
    sc[i] = s;
    sh[i] = b1[i] * s + beta[i];
  }
}

// Pack W1 [64][128] and W2 [128][64] into MFMA B-fragment order, hi/lo bf16 split.
__global__ void k_prepw(const float* __restrict__ W1, const float* __restrict__ W2,
                        uint4* __restrict__ w1h, uint4* __restrict__ w1l,
                        uint4* __restrict__ w2h, uint4* __restrict__ w2l) {
  int p = blockIdx.x * 256 + threadIdx.x;  // 0..2047
  if (p >= 2048) return;
  int lane = p & 63;
  int c = lane & 15, g = lane >> 4;
  unsigned short hh[8], ll[8];
  if (p < 1024) {
    int nt = p >> 7, f = (p >> 6) & 1;
    int nn = nt * 16 + c, kb = f * 32 + g * 8;
#pragma unroll
    for (int e = 0; e < 8; ++e) {
      float w = W1[(kb + e) * TWO_DIM + nn];
      hh[e] = f2bf(w);
      ll[e] = f2bf(w - bf2f(hh[e]));
    }
    w1h[p] = pack8(hh);
    w1l[p] = pack8(ll);
  } else {
    int q = p - 1024;
    int nt = q >> 8, f = (q >> 6) & 3;
    int nn = nt * 16 + c, kb = f * 32 + g * 8;
#pragma unroll
    for (int e = 0; e < 8; ++e) {
      float w = W2[(kb + e) * DIM + nn];
      hh[e] = f2bf(w);
      ll[e] = f2bf(w - bf2f(hh[e]));
    }
    w2h[q] = pack8(hh);
    w2l[q] = pack8(ll);
  }
}

// v = (1+eps)*x + agg, split hi/lo bf16, packed in MFMA A-frag order.
__global__ void k_split(const float* __restrict__ xin, const float* __restrict__ agg,
                        const float* __restrict__ epsp, uint4* __restrict__ vh,
                        uint4* __restrict__ vl, int n, int P) {
  int p = blockIdx.x * 256 + threadIdx.x;
  if (p >= P) return;
  float ep = 1.0f + epsp[0];
  int lane = p & 63;
  int T = p >> 7;
  int f = (p >> 6) & 1;
  int m = T * 16 + (lane & 15);
  int k0 = f * 32 + (lane >> 4) * 8;
  float v[8];
  if (m < n) {
    const float4* xa = reinterpret_cast<const float4*>(xin + (size_t)m * DIM + k0);
    const float4* aa = reinterpret_cast<const float4*>(agg + (size_t)m * DIM + k0);
    float4 x0 = xa[0], x1 = xa[1], a0 = aa[0], a1 = aa[1];
    v[0] = ep * x0.x + a0.x; v[1] = ep * x0.y + a0.y;
    v[2] = ep * x0.z + a0.z; v[3] = ep * x0.w + a0.w;
    v[4] = ep * x1.x + a1.x; v[5] = ep * x1.y + a1.y;
    v[6] = ep * x1.z + a1.z; v[7] = ep * x1.w + a1.w;
  } else {
#pragma unroll
    for (int e = 0; e < 8; ++e) v[e] = 0.0f;
  }
  unsigned short hh[8], ll[8];
#pragma unroll
  for (int e = 0; e < 8; ++e) {
    hh[e] = f2bf(v[e]);
    ll[e] = f2bf(v[e] - bf2f(hh[e]));
  }
  vh[p] = pack8(hh);
  vl[p] = pack8(ll);
}

// GEMM1 + BN + tanh + split + repack for GEMM2.
__launch_bounds__(256, 2)
__global__ void k_g1(const uint4* __restrict__ vh, const uint4* __restrict__ vl,
                     const uint4* __restrict__ w1h, const uint4* __restrict__ w1l,
                     const float* __restrict__ sc, const float* __restrict__ sh,
                     uint4* __restrict__ hh, uint4* __restrict__ hl, int NTiles) {
  __shared__ uint4 sBh[1024], sBl[1024];
  __shared__ float ssc[TWO_DIM], ssh[TWO_DIM];
  __shared__ float sH[4 * 16 * 132];

  int t = threadIdx.x;
#pragma unroll
  for (int q = 0; q < 4; ++q) {
    sBh[q * 256 + t] = w1h[q * 256 + t];
    sBl[q * 256 + t] = w1l[q * 256 + t];
  }
  if (t < TWO_DIM) {
    ssc[t] = sc[t];
    ssh[t] = sh[t];
  }
  __syncthreads();

  const int wid = t >> 6, lane = t & 63;
  const int T = blockIdx.x * 4 + wid;
  if (T >= NTiles) return;
  const int c = lane & 15, g = lane >> 4;

  const bf16x8* Ah = reinterpret_cast<const bf16x8*>(vh + (size_t)T * 128);
  const bf16x8* Al = reinterpret_cast<const bf16x8*>(vl + (size_t)T * 128);
  bf16x8 ah0 = Ah[lane], ah1 = Ah[64 + lane];
  bf16x8 al0 = Al[lane], al1 = Al[64 + lane];

  const bf16x8* Bh = reinterpret_cast<const bf16x8*>(sBh);
  const bf16x8* Bl = reinterpret_cast<const bf16x8*>(sBl);
  float* myH = sH + wid * (16 * 132);

#pragma unroll
  for (int nt = 0; nt < 8; ++nt) {
    f32x4 acc = {0.f, 0.f, 0.f, 0.f};
    bf16x8 bh0 = Bh[(nt * 2 + 0) * 64 + lane];
    bf16x8 bl0 = Bl[(nt * 2 + 0) * 64 + lane];
    bf16x8 bh1 = Bh[(nt * 2 + 1) * 64 + lane];
    bf16x8 bl1 = Bl[(nt * 2 + 1) * 64 + lane];
    acc = MFMA16(ah0, bh0, acc);
    acc = MFMA16(ah1, bh1, acc);
    acc = MFMA16(ah0, bl0, acc);
    acc = MFMA16(ah1, bl1, acc);
    acc = MFMA16(al0, bh0, acc);
    acc = MFMA16(al1, bh1, acc);
    int j = nt * 16 + c;
    float scj = ssc[j], shj = ssh[j];
#pragma unroll
    for (int r = 0; r < 4; ++r)
      myH[(g * 4 + r) * 132 + j] = fast_tanh(acc[r] * scj + shj);
  }

#pragma unroll
  for (int f2 = 0; f2 < 4; ++f2) {
    const float* hp = myH + c * 132 + f2 * 32 + g * 8;
    float4 v0 = *reinterpret_cast<const float4*>(hp);
    float4 v1 = *reinterpret_cast<const float4*>(hp + 4);
    float vv[8] = {v0.x, v0.y, v0.z, v0.w, v1.x, v1.y, v1.z, v1.w};
    unsigned short H[8], L[8];
#pragma unroll
    for (int e = 0; e < 8; ++e) {
      H[e] = f2bf(vv[e]);
      L[e] = f2bf(vv[e] - bf2f(H[e]));
    }
    size_t o = ((size_t)T * 4 + f2) * 64 + lane;
    hh[o] = pack8(H);
    hl[o] = pack8(L);
  }
}

// GEMM2 + tanh (+pool). C = H[16x128] @ W2[128x64].
template <bool POOL>
__launch_bounds__(256, 2)
__global__ void k_g2(const uint4* __restrict__ hh, const uint4* __restrict__ hl,
                     const uint4* __restrict__ w2h, const uint4* __restrict__ w2l,
                     const float* __restrict__ b2, float* __restrict__ hout,
                     float* __restrict__ pooled, const int* __restrict__ batch,
                     int n, int NTiles) {
  __shared__ uint4 sBh[1024], sBl[1024];
  __shared__ float sb2[DIM];

  int t = threadIdx.x;
#pragma unroll
  for (int q = 0; q < 4; ++q) {
    sBh[q * 256 + t] = w2h[q * 256 + t];
    sBl[q * 256 + t] = w2l[q * 256 + t];
  }
  if (t < DIM) sb2[t] = b2[t];
  __syncthreads();

  const int wid = t >> 6, lane = t & 63;
  const int T = blockIdx.x * 4 + wid;
  if (T >= NTiles) return;
  const int c = lane & 15, g = lane >> 4;

  const bf16x8* Ah = reinterpret_cast<const bf16x8*>(hh + (size_t)T * 256);
  const bf16x8* Al = reinterpret_cast<const bf16x8*>(hl + (size_t)T * 256);
  bf16x8 ah0 = Ah[lane], ah1 = Ah[64 + lane], ah2 = Ah[128 + lane], ah3 = Ah[192 + lane];
  bf16x8 al0 = Al[lane], al1 = Al[64 + lane], al2 = Al[128 + lane], al3 = Al[192 + lane];

  const bf16x8* Bh = reinterpret_cast<const bf16x8*>(sBh);
  const bf16x8* Bl = reinterpret_cast<const bf16x8*>(sBl);

  bool uni = false;
  int b0 = 0;
  if (POOL) {
    b0 = batch[min(T * 16, n - 1)];
    int b15 = batch[min(T * 16 + 15, n - 1)];
    uni = (b0 == b15) && (T * 16 + 15 < n);
  }

#pragma unroll
  for (int nt = 0; nt < 4; ++nt) {
    f32x4 acc = {0.f, 0.f, 0.f, 0.f};
    bf16x8 bh0 = Bh[(nt * 4 + 0) * 64 + lane];
    bf16x8 bh1 = Bh[(nt * 4 + 1) * 64 + lane];
    bf16x8 bh2 = Bh[(nt * 4 + 2) * 64 + lane];
    bf16x8 bh3 = Bh[(nt * 4 + 3) * 64 + lane];
    bf16x8 bl0 = Bl[(nt * 4 + 0) * 64 + lane];
    bf16x8 bl1 = Bl[(nt * 4 + 1) * 64 + lane];
    bf16x8 bl2 = Bl[(nt * 4 + 2) * 64 + lane];
    bf16x8 bl3 = Bl[(nt * 4 + 3) * 64 + lane];
    acc = MFMA16(ah0, bh0, acc);
    acc = MFMA16(ah1, bh1, acc);
    acc = MFMA16(ah2, bh2, acc);
    acc = MFMA16(ah3, bh3, acc);
    acc = MFMA16(ah0, bl0, acc);
    acc = MFMA16(ah1, bl1, acc);
    acc = MFMA16(ah2, bl2, acc);
    acc = MFMA16(ah3, bl3, acc);
    acc = MFMA16(al0, bh0, acc);
    acc = MFMA16(al1, bh1, acc);
    acc = MFMA16(al2, bh2, acc);
    acc = MFMA16(al3, bh3, acc);

    int j = nt * 16 + c;
    float bj = sb2[j];
    float o0 = fast_tanh(acc[0] + bj);
    float o1 = fast_tanh(acc[1] + bj);
    float o2 = fast_tanh(acc[2] + bj);
    float o3 = fast_tanh(acc[3] + bj);
    if (POOL) {
      if (uni) {
        float os = (o0 + o1) + (o2 + o3);
        os += __shfl_xor(os, 16);
        os += __shfl_xor(os, 32);
        if (g == 0) atomicAdd(&pooled[(size_t)b0 * DIM + j], os);
      } else {
        int mb = T * 16 + g * 4;
#pragma unroll
        for (int r = 0; r < 4; ++r) {
          int m = mb + r;
          float o = (r == 0) ? o0 : (r == 1) ? o1 : (r == 2) ? o2 : o3;
          if (m < n) atomicAdd(&pooled[(size_t)batch[m] * DIM + j], o);
        }
      }
    } else {
      int mb = T * 16 + g * 4;
      if (mb + 0 < n) hout[(size_t)(mb + 0) * DIM + j] = o0;
      if (mb + 1 < n) hout[(size_t)(mb + 1) * DIM + j] = o1;
      if (mb + 2 < n) hout[(size_t)(mb + 2) * DIM + j] = o2;
      if (mb + 3 < n) hout[(size_t)(mb + 3) * DIM + j] = o3;
    }
  }
}

// out[g][i] = tanh( (pooled[g]/max(cnt,1)) . linW[:,i] + linb[i] )
__global__ void k_out(const float* __restrict__ pooled, const int* __restrict__ cnt,
                      const float* __restrict__ linW, const float* __restrict__ linb,
                      float* __restrict__ out) {
  int g = blockIdx.x;
  int i = threadIdx.x;
  int c = cnt[g];
  float inv = 1.0f / (float)(c > 0 ? c : 1);
  float acc = 0.0f;
#pragma unroll
  for (int k = 0; k < DIM; ++k)
    acc += pooled[(size_t)g * DIM + k] * linW[k * DIM + i];
  out[(size_t)g * DIM + i] = fast_tanh(acc * inv + linb[i]);
}

extern "C" void kernel_launch(void* const* d_in, const int* in_sizes, int n_in,
                              void* d_out, int out_size, void* d_ws, size_t ws_size,
                              hipStream_t stream) {
  const float* x = (const float*)d_in[0];
  const int* ei = (const int*)d_in[1];
  const int* batch = (const int*)d_in[2];
  const float* eps1 = (const float*)d_in[3];
  const float* W11 = (const float*)d_in[4];
  const float* b11 = (const float*)d_in[5];
  const float* g1 = (const float*)d_in[6];
  const float* be1 = (const float*)d_in[7];
  const float* W12 = (const float*)d_in[8];
  const float* b12 = (const float*)d_in[9];
  const float* eps2 = (const float*)d_in[10];
  const float* W21 = (const float*)d_in[11];
  const float* b21 = (const float*)d_in[12];
  const float* g2 = (const float*)d_in[13];
  const float* be2 = (const float*)d_in[14];
  const float* W22 = (const float*)d_in[15];
  const float* b22 = (const float*)d_in[16];
  const float* linW = (const float*)d_in[17];
  const float* linb = (const float*)d_in[18];

  const int n = in_sizes[0] / DIM;  // 100000
  const int E = in_sizes[1] / 2;    // 1600000
  const int G = out_size / DIM;     // 256
  const int* src = ei;
  const int* dst = ei + E;
  const int NT = (n + 15) / 16;     // 6250
  const int P = NT * 128;

  size_t off = 0;
  auto alloc = [&](size_t bytes) -> void* {
    void* p = (char*)d_ws + off;
    off += (bytes + 255) & ~(size_t)255;
    return p;
  };
  float* agg = (float*)alloc((size_t)n * DIM * 4);
  float* h1 = (float*)alloc((size_t)n * DIM * 4);
  uint4* vhi = (uint4*)alloc((size_t)P * 16);
  uint4* vlo = (uint4*)alloc((size_t)P * 16);
  uint4* hhi = (uint4*)alloc((size_t)NT * 256 * 16);
  uint4* hlo = (uint4*)alloc((size_t)NT * 256 * 16);
  int* deg = (int*)alloc((size_t)n * 4);
  int* offs = (int*)alloc((size_t)n * 4);
  int* cursor = (int*)alloc((size_t)n * 4);
  int* csr = (int*)alloc((size_t)E * 4);
  float* sc1 = (float*)alloc(TWO_DIM * 4);
  float* sh1 = (float*)alloc(TWO_DIM * 4);
  float* sc2 = (float*)alloc(TWO_DIM * 4);
  float* sh2 = (float*)alloc(TWO_DIM * 4);
  uint4* w1hA = (uint4*)alloc(1024 * 16);
  uint4* w1lA = (uint4*)alloc(1024 * 16);
  uint4* w2hA = (uint4*)alloc(1024 * 16);
  uint4* w2lA = (uint4*)alloc(1024 * 16);
  uint4* w1hB = (uint4*)alloc(1024 * 16);
  uint4* w1lB = (uint4*)alloc(1024 * 16);
  uint4* w2hB = (uint4*)alloc(1024 * 16);
  uint4* w2lB = (uint4*)alloc(1024 * 16);
  float* pooled = (float*)alloc((size_t)G * DIM * 4);
  int* cnt = (int*)alloc((size_t)G * 4);
  int* bsum = (int*)alloc(512 * 4);

  hipMemsetAsync(deg, 0, (size_t)n * 4, stream);
  hipMemsetAsync(cnt, 0, (size_t)G * 4, stream);
  hipMemsetAsync(pooled, 0, (size_t)G * DIM * 4, stream);

  const int nb = (n + 255) / 256;
  k_hist<<<1024, 256, 0, stream>>>(dst, deg, E);
  k_hist<<<256, 256, 0, stream>>>(batch, cnt, n);
  k_scan_part<<<nb, 256, 0, stream>>>(deg, bsum, n);
  k_scan_mid<<<1, 512, 0, stream>>>(bsum, nb);
  k_scan_final<<<nb, 256, 0, stream>>>(deg, bsum, offs, cursor, n);
  k_scatter<<<1024, 256, 0, stream>>>(src, dst, cursor, csr, E);
  k_prep<<<1, TWO_DIM, 0, stream>>>(b11, g1, be1, sc1, sh1);
  k_prep<<<1, TWO_DIM, 0, stream>>>(b21, g2, be2, sc2, sh2);
  k_prepw<<<8, 256, 0, stream>>>(W11, W12, w1hA, w1lA, w2hA, w2lA);
  k_prepw<<<8, 256, 0, stream>>>(W21, W22, w1hB, w1lB, w2hB, w2lB);

  const int gT = (NT + 3) / 4;
  // GIN layer 1
  k_gather<<<(n + 3) / 4, 256, 0, stream>>>(x, csr, offs, deg, agg, n);
  k_split<<<(P + 255) / 256, 256, 0, stream>>>(x, agg, eps1, vhi, vlo, n, P);
  k_g1<<<gT, 256, 0, stream>>>(vhi, vlo, w1hA, w1lA, sc1, sh1, hhi, hlo, NT);
  k_g2<false><<<gT, 256, 0, stream>>>(hhi, hlo, w2hA, w2lA, b12, h1, nullptr,
                                      nullptr, n, NT);
  // GIN layer 2
  k_gather<<<(n + 3) / 4, 256, 0, stream>>>(h1, csr, offs, deg, agg, n);
  k_split<<<(P + 255) / 256, 256, 0, stream>>>(h1, agg, eps2, vhi, vlo, n, P);
  k_g1<<<gT, 256, 0, stream>>>(vhi, vlo, w1hB, w1lB, sc2, sh2, hhi, hlo, NT);
  k_g2<true><<<gT, 256, 0, stream>>>(hhi, hlo, w2hB, w2lB, b22, nullptr, pooled,
                                     batch, n, NT);
  k_out<<<G, DIM, 0, stream>>>(pooled, cnt, linW, linb, (float*)d_out);
}

// Round 8
// 592.754 us; speedup vs baseline: 2.2026x; 1.0922x over previous
//
#include <hip/hip_runtime.h>

#define DIM 64
#define TWO_DIM 128

typedef __attribute__((ext_vector_type(8))) short bf16x8;
typedef __attribute__((ext_vector_type(4))) float f32x4;
#define MFMA16(A, B, C) __builtin_amdgcn_mfma_f32_16x16x32_bf16(A, B, C, 0, 0, 0)

__device__ __forceinline__ float fast_tanh(float x) {
  float cx = fminf(fmaxf(x, -15.0f), 15.0f);
  float e = __expf(2.0f * cx);
  return (e - 1.0f) / (e + 1.0f);
}

__device__ __forceinline__ unsigned short f2bf(float x) {
  unsigned int b = __float_as_uint(x);
  unsigned int r = b + 0x7FFFu + ((b >> 16) & 1u);
  return (unsigned short)(r >> 16);
}
__device__ __forceinline__ float bf2f(unsigned short h) {
  return __uint_as_float(((unsigned int)h) << 16);
}
__device__ __forceinline__ uint4 pack8(const unsigned short* s) {
  uint4 u;
  u.x = (unsigned)s[0] | ((unsigned)s[1] << 16);
  u.y = (unsigned)s[2] | ((unsigned)s[3] << 16);
  u.z = (unsigned)s[4] | ((unsigned)s[5] << 16);
  u.w = (unsigned)s[6] | ((unsigned)s[7] << 16);
  return u;
}

// ---------------- graph machinery ----------------
// grid-stride histogram, int4 loads, 4 atomics in flight per iter
__global__ void k_hist(const int* __restrict__ idx, int* __restrict__ cnt, int n) {
  int tid = blockIdx.x * blockDim.x + threadIdx.x;
  int stride = gridDim.x * blockDim.x;
  int n4 = n >> 2;
  const int4* p = reinterpret_cast<const int4*>(idx);
  for (int i = tid; i < n4; i += stride) {
    int4 v = p[i];
    atomicAdd(&cnt[v.x], 1);
    atomicAdd(&cnt[v.y], 1);
    atomicAdd(&cnt[v.z], 1);
    atomicAdd(&cnt[v.w], 1);
  }
  if (tid == 0) {
    for (int i = n4 << 2; i < n; ++i) atomicAdd(&cnt[idx[i]], 1);
  }
}

__global__ void k_scan_part(const int* __restrict__ deg, int* __restrict__ bsum,
                            int n) {
  __shared__ int red[256];
  int t = threadIdx.x;
  int i = blockIdx.x * 256 + t;
  red[t] = (i < n) ? deg[i] : 0;
  __syncthreads();
#pragma unroll
  for (int off = 128; off >= 1; off >>= 1) {
    if (t < off) red[t] += red[t + off];
    __syncthreads();
  }
  if (t == 0) bsum[blockIdx.x] = red[0];
}

__global__ void k_scan_mid(int* __restrict__ bsum, int nb) {
  __shared__ int s[512];
  int t = threadIdx.x;
  int v = (t < nb) ? bsum[t] : 0;
  s[t] = v;
  __syncthreads();
#pragma unroll
  for (int off = 1; off < 512; off <<= 1) {
    int u = (t >= off) ? s[t - off] : 0;
    __syncthreads();
    s[t] += u;
    __syncthreads();
  }
  if (t < nb) bsum[t] = s[t] - v;
}

__global__ void k_scan_final(const int* __restrict__ deg, const int* __restrict__ bsum,
                             int* __restrict__ offs, int* __restrict__ cursor, int n) {
  __shared__ int s[256];
  int t = threadIdx.x;
  int i = blockIdx.x * 256 + t;
  int d = (i < n) ? deg[i] : 0;
  s[t] = d;
  __syncthreads();
#pragma unroll
  for (int off = 1; off < 256; off <<= 1) {
    int u = (t >= off) ? s[t - off] : 0;
    __syncthreads();
    s[t] += u;
    __syncthreads();
  }
  int ex = bsum[blockIdx.x] + s[t] - d;
  if (i < n) {
    offs[i] = ex;
    cursor[i] = ex;
  }
}

// Dst-range-partitioned scatter: blocks with (blockIdx&7)==r handle only edges
// whose dst falls in node-range r. Assuming consecutive blockIdx round-robins
// across the 8 XCDs, each 0.8 MB csr window is written from a single XCD's L2,
// so cachelines fill before eviction (kills the 17x write amplification seen
// in round 7). Correctness does NOT depend on the XCD mapping.
__global__ void k_scatter(const int* __restrict__ src, const int* __restrict__ dst,
                          int* __restrict__ cursor, int* __restrict__ csr, int E,
                          int n) {
  const int r = blockIdx.x & 7;
  const int sub = blockIdx.x >> 3;
  const int nsub = gridDim.x >> 3;
  const int span = (n + 7) >> 3;
  const int lo = r * span;
  const int hi = min(n, lo + span);

  int tid = sub * blockDim.x + threadIdx.x;
  int stride = nsub * blockDim.x;
  int E4 = E >> 2;
  const int4* s4 = reinterpret_cast<const int4*>(src);
  const int4* d4 = reinterpret_cast<const int4*>(dst);
  for (int i = tid; i < E4; i += stride) {
    int4 d = d4[i];
    bool a0 = (d.x >= lo) & (d.x < hi);
    bool a1 = (d.y >= lo) & (d.y < hi);
    bool a2 = (d.z >= lo) & (d.z < hi);
    bool a3 = (d.w >= lo) & (d.w < hi);
    if (a0 | a1 | a2 | a3) {
      int4 s = s4[i];
      if (a0) { int p = atomicAdd(&cursor[d.x], 1); csr[p] = s.x; }
      if (a1) { int p = atomicAdd(&cursor[d.y], 1); csr[p] = s.y; }
      if (a2) { int p = atomicAdd(&cursor[d.z], 1); csr[p] = s.z; }
      if (a3) { int p = atomicAdd(&cursor[d.w], 1); csr[p] = s.w; }
    }
  }
  if (blockIdx.x == 0 && threadIdx.x == 0) {
    for (int i = E4 << 2; i < E; ++i) {
      int p = atomicAdd(&cursor[dst[i]], 1);
      csr[p] = src[i];
    }
  }
}

// one 64-lane wave per node; lane = feature
__global__ void k_gather(const float* __restrict__ x, const int* __restrict__ csr,
                         const int* __restrict__ offs, const int* __restrict__ deg,
                         float* __restrict__ agg, int n) {
  int node = blockIdx.x * 4 + (threadIdx.x >> 6);
  int t = threadIdx.x & 63;
  if (node >= n) return;
  int s = offs[node], d = deg[node];
  float acc = 0.0f;
  for (int base = 0; base < d; base += 64) {
    int m = min(64, d - base);
    int myi = (t < m) ? csr[s + base + t] : 0;
    for (int i = 0; i < m; ++i) {
      int sn = __shfl(myi, i);
      acc += x[(size_t)sn * DIM + t];
    }
  }
  agg[(size_t)node * DIM + t] = acc;
}

// fold BN(eval) into scale/shift
__global__ void k_prep(const float* __restrict__ b1, const float* __restrict__ gamma,
                       const float* __restrict__ beta, float* __restrict__ sc,
                       float* __restrict__ sh) {
  int i = threadIdx.x;
  if (i < TWO_DIM) {
    float s = gamma[i] * rsqrtf(1.0f + 1e-5f);
    sc[i] = s;
    sh[i] = b1[i] * s + beta[i];
  }
}

// Pack W1 [64][128] and W2 [128][64] into MFMA B-fragment order, hi/lo bf16 split.
__global__ void k_prepw(const float* __restrict__ W1, const float* __restrict__ W2,
                        uint4* __restrict__ w1h, uint4* __restrict__ w1l,
                        uint4* __restrict__ w2h, uint4* __restrict__ w2l) {
  int p = blockIdx.x * 256 + threadIdx.x;  // 0..2047
  if (p >= 2048) return;
  int lane = p & 63;
  int c = lane & 15, g = lane >> 4;
  unsigned short hh[8], ll[8];
  if (p < 1024) {
    int nt = p >> 7, f = (p >> 6) & 1;
    int nn = nt * 16 + c, kb = f * 32 + g * 8;
#pragma unroll
    for (int e = 0; e < 8; ++e) {
      float w = W1[(kb + e) * TWO_DIM + nn];
      hh[e] = f2bf(w);
      ll[e] = f2bf(w - bf2f(hh[e]));
    }
    w1h[p] = pack8(hh);
    w1l[p] = pack8(ll);
  } else {
    int q = p - 1024;
    int nt = q >> 8, f = (q >> 6) & 3;
    int nn = nt * 16 + c, kb = f * 32 + g * 8;
#pragma unroll
    for (int e = 0; e < 8; ++e) {
      float w = W2[(kb + e) * DIM + nn];
      hh[e] = f2bf(w);
      ll[e] = f2bf(w - bf2f(hh[e]));
    }
    w2h[q] = pack8(hh);
    w2l[q] = pack8(ll);
  }
}

// v = (1+eps)*x + agg, split hi/lo bf16, packed in MFMA A-frag order.
__global__ void k_split(const float* __restrict__ xin, const float* __restrict__ agg,
                        const float* __restrict__ epsp, uint4* __restrict__ vh,
                        uint4* __restrict__ vl, int n, int P) {
  int p = blockIdx.x * 256 + threadIdx.x;
  if (p >= P) return;
  float ep = 1.0f + epsp[0];
  int lane = p & 63;
  int T = p >> 7;
  int f = (p >> 6) & 1;
  int m = T * 16 + (lane & 15);
  int k0 = f * 32 + (lane >> 4) * 8;
  float v[8];
  if (m < n) {
    const float4* xa = reinterpret_cast<const float4*>(xin + (size_t)m * DIM + k0);
    const float4* aa = reinterpret_cast<const float4*>(agg + (size_t)m * DIM + k0);
    float4 x0 = xa[0], x1 = xa[1], a0 = aa[0], a1 = aa[1];
    v[0] = ep * x0.x + a0.x; v[1] = ep * x0.y + a0.y;
    v[2] = ep * x0.z + a0.z; v[3] = ep * x0.w + a0.w;
    v[4] = ep * x1.x + a1.x; v[5] = ep * x1.y + a1.y;
    v[6] = ep * x1.z + a1.z; v[7] = ep * x1.w + a1.w;
  } else {
#pragma unroll
    for (int e = 0; e < 8; ++e) v[e] = 0.0f;
  }
  unsigned short hh[8], ll[8];
#pragma unroll
  for (int e = 0; e < 8; ++e) {
    hh[e] = f2bf(v[e]);
    ll[e] = f2bf(v[e] - bf2f(hh[e]));
  }
  vh[p] = pack8(hh);
  vl[p] = pack8(ll);
}

// GEMM1 + BN + tanh + split + repack for GEMM2.
__launch_bounds__(256, 2)
__global__ void k_g1(const uint4* __restrict__ vh, const uint4* __restrict__ vl,
                     const uint4* __restrict__ w1h, const uint4* __restrict__ w1l,
                     const float* __restrict__ sc, const float* __restrict__ sh,
                     uint4* __restrict__ hh, uint4* __restrict__ hl, int NTiles) {
  __shared__ uint4 sBh[1024], sBl[1024];
  __shared__ float ssc[TWO_DIM], ssh[TWO_DIM];
  __shared__ float sH[4 * 16 * 132];

  int t = threadIdx.x;
#pragma unroll
  for (int q = 0; q < 4; ++q) {
    sBh[q * 256 + t] = w1h[q * 256 + t];
    sBl[q * 256 + t] = w1l[q * 256 + t];
  }
  if (t < TWO_DIM) {
    ssc[t] = sc[t];
    ssh[t] = sh[t];
  }
  __syncthreads();

  const int wid = t >> 6, lane = t & 63;
  const int T = blockIdx.x * 4 + wid;
  if (T >= NTiles) return;
  const int c = lane & 15, g = lane >> 4;

  const bf16x8* Ah = reinterpret_cast<const bf16x8*>(vh + (size_t)T * 128);
  const bf16x8* Al = reinterpret_cast<const bf16x8*>(vl + (size_t)T * 128);
  bf16x8 ah0 = Ah[lane], ah1 = Ah[64 + lane];
  bf16x8 al0 = Al[lane], al1 = Al[64 + lane];

  const bf16x8* Bh = reinterpret_cast<const bf16x8*>(sBh);
  const bf16x8* Bl = reinterpret_cast<const bf16x8*>(sBl);
  float* myH = sH + wid * (16 * 132);

#pragma unroll
  for (int nt = 0; nt < 8; ++nt) {
    f32x4 acc = {0.f, 0.f, 0.f, 0.f};
    bf16x8 bh0 = Bh[(nt * 2 + 0) * 64 + lane];
    bf16x8 bl0 = Bl[(nt * 2 + 0) * 64 + lane];
    bf16x8 bh1 = Bh[(nt * 2 + 1) * 64 + lane];
    bf16x8 bl1 = Bl[(nt * 2 + 1) * 64 + lane];
    acc = MFMA16(ah0, bh0, acc);
    acc = MFMA16(ah1, bh1, acc);
    acc = MFMA16(ah0, bl0, acc);
    acc = MFMA16(ah1, bl1, acc);
    acc = MFMA16(al0, bh0, acc);
    acc = MFMA16(al1, bh1, acc);
    int j = nt * 16 + c;
    float scj = ssc[j], shj = ssh[j];
#pragma unroll
    for (int r = 0; r < 4; ++r)
      myH[(g * 4 + r) * 132 + j] = fast_tanh(acc[r] * scj + shj);
  }

#pragma unroll
  for (int f2 = 0; f2 < 4; ++f2) {
    const float* hp = myH + c * 132 + f2 * 32 + g * 8;
    float4 v0 = *reinterpret_cast<const float4*>(hp);
    float4 v1 = *reinterpret_cast<const float4*>(hp + 4);
    float vv[8] = {v0.x, v0.y, v0.z, v0.w, v1.x, v1.y, v1.z, v1.w};
    unsigned short H[8], L[8];
#pragma unroll
    for (int e = 0; e < 8; ++e) {
      H[e] = f2bf(vv[e]);
      L[e] = f2bf(vv[e] - bf2f(H[e]));
    }
    size_t o = ((size_t)T * 4 + f2) * 64 + lane;
    hh[o] = pack8(H);
    hl[o] = pack8(L);
  }
}

// GEMM2 + tanh (+pool). C = H[16x128] @ W2[128x64].
template <bool POOL>
__launch_bounds__(256, 2)
__global__ void k_g2(const uint4* __restrict__ hh, const uint4* __restrict__ hl,
                     const uint4* __restrict__ w2h, const uint4* __restrict__ w2l,
                     const float* __restrict__ b2, float* __restrict__ hout,
                     float* __restrict__ pooled, const int* __restrict__ batch,
                     int n, int NTiles) {
  __shared__ uint4 sBh[1024], sBl[1024];
  __shared__ float sb2[DIM];

  int t = threadIdx.x;
#pragma unroll
  for (int q = 0; q < 4; ++q) {
    sBh[q * 256 + t] = w2h[q * 256 + t];
    sBl[q * 256 + t] = w2l[q * 256 + t];
  }
  if (t < DIM) sb2[t] = b2[t];
  __syncthreads();

  const int wid = t >> 6, lane = t & 63;
  const int T = blockIdx.x * 4 + wid;
  if (T >= NTiles) return;
  const int c = lane & 15, g = lane >> 4;

  const bf16x8* Ah = reinterpret_cast<const bf16x8*>(hh + (size_t)T * 256);
  const bf16x8* Al = reinterpret_cast<const bf16x8*>(hl + (size_t)T * 256);
  bf16x8 ah0 = Ah[lane], ah1 = Ah[64 + lane], ah2 = Ah[128 + lane], ah3 = Ah[192 + lane];
  bf16x8 al0 = Al[lane], al1 = Al[64 + lane], al2 = Al[128 + lane], al3 = Al[192 + lane];

  const bf16x8* Bh = reinterpret_cast<const bf16x8*>(sBh);
  const bf16x8* Bl = reinterpret_cast<const bf16x8*>(sBl);

  bool uni = false;
  int b0 = 0;
  if (POOL) {
    b0 = batch[min(T * 16, n - 1)];
    int b15 = batch[min(T * 16 + 15, n - 1)];
    uni = (b0 == b15) && (T * 16 + 15 < n);
  }

#pragma unroll
  for (int nt = 0; nt < 4; ++nt) {
    f32x4 acc = {0.f, 0.f, 0.f, 0.f};
    bf16x8 bh0 = Bh[(nt * 4 + 0) * 64 + lane];
    bf16x8 bh1 = Bh[(nt * 4 + 1) * 64 + lane];
    bf16x8 bh2 = Bh[(nt * 4 + 2) * 64 + lane];
    bf16x8 bh3 = Bh[(nt * 4 + 3) * 64 + lane];
    bf16x8 bl0 = Bl[(nt * 4 + 0) * 64 + lane];
    bf16x8 bl1 = Bl[(nt * 4 + 1) * 64 + lane];
    bf16x8 bl2 = Bl[(nt * 4 + 2) * 64 + lane];
    bf16x8 bl3 = Bl[(nt * 4 + 3) * 64 + lane];
    acc = MFMA16(ah0, bh0, acc);
    acc = MFMA16(ah1, bh1, acc);
    acc = MFMA16(ah2, bh2, acc);
    acc = MFMA16(ah3, bh3, acc);
    acc = MFMA16(ah0, bl0, acc);
    acc = MFMA16(ah1, bl1, acc);
    acc = MFMA16(ah2, bl2, acc);
    acc = MFMA16(ah3, bl3, acc);
    acc = MFMA16(al0, bh0, acc);
    acc = MFMA16(al1, bh1, acc);
    acc = MFMA16(al2, bh2, acc);
    acc = MFMA16(al3, bh3, acc);

    int j = nt * 16 + c;
    float bj = sb2[j];
    float o0 = fast_tanh(acc[0] + bj);
    float o1 = fast_tanh(acc[1] + bj);
    float o2 = fast_tanh(acc[2] + bj);
    float o3 = fast_tanh(acc[3] + bj);
    if (POOL) {
      if (uni) {
        float os = (o0 + o1) + (o2 + o3);
        os += __shfl_xor(os, 16);
        os += __shfl_xor(os, 32);
        if (g == 0) atomicAdd(&pooled[(size_t)b0 * DIM + j], os);
      } else {
        int mb = T * 16 + g * 4;
#pragma unroll
        for (int r = 0; r < 4; ++r) {
          int m = mb + r;
          float o = (r == 0) ? o0 : (r == 1) ? o1 : (r == 2) ? o2 : o3;
          if (m < n) atomicAdd(&pooled[(size_t)batch[m] * DIM + j], o);
        }
      }
    } else {
      int mb = T * 16 + g * 4;
      if (mb + 0 < n) hout[(size_t)(mb + 0) * DIM + j] = o0;
      if (mb + 1 < n) hout[(size_t)(mb + 1) * DIM + j] = o1;
      if (mb + 2 < n) hout[(size_t)(mb + 2) * DIM + j] = o2;
      if (mb + 3 < n) hout[(size_t)(mb + 3) * DIM + j] = o3;
    }
  }
}

// out[g][i] = tanh( (pooled[g]/max(cnt,1)) . linW[:,i] + linb[i] )
__global__ void k_out(const float* __restrict__ pooled, const int* __restrict__ cnt,
                      const float* __restrict__ linW, const float* __restrict__ linb,
                      float* __restrict__ out) {
  int g = blockIdx.x;
  int i = threadIdx.x;
  int c = cnt[g];
  float inv = 1.0f / (float)(c > 0 ? c : 1);
  float acc = 0.0f;
#pragma unroll
  for (int k = 0; k < DIM; ++k)
    acc += pooled[(size_t)g * DIM + k] * linW[k * DIM + i];
  out[(size_t)g * DIM + i] = fast_tanh(acc * inv + linb[i]);
}

extern "C" void kernel_launch(void* const* d_in, const int* in_sizes, int n_in,
                              void* d_out, int out_size, void* d_ws, size_t ws_size,
                              hipStream_t stream) {
  const float* x = (const float*)d_in[0];
  const int* ei = (const int*)d_in[1];
  const int* batch = (const int*)d_in[2];
  const float* eps1 = (const float*)d_in[3];
  const float* W11 = (const float*)d_in[4];
  const float* b11 = (const float*)d_in[5];
  const float* g1 = (const float*)d_in[6];
  const float* be1 = (const float*)d_in[7];
  const float* W12 = (const float*)d_in[8];
  const float* b12 = (const float*)d_in[9];
  const float* eps2 = (const float*)d_in[10];
  const float* W21 = (const float*)d_in[11];
  const float* b21 = (const float*)d_in[12];
  const float* g2 = (const float*)d_in[13];
  const float* be2 = (const float*)d_in[14];
  const float* W22 = (const float*)d_in[15];
  const float* b22 = (const float*)d_in[16];
  const float* linW = (const float*)d_in[17];
  const float* linb = (const float*)d_in[18];

  const int n = in_sizes[0] / DIM;  // 100000
  const int E = in_sizes[1] / 2;    // 1600000
  const int G = out_size / DIM;     // 256
  const int* src = ei;
  const int* dst = ei + E;
  const int NT = (n + 15) / 16;     // 6250
  const int P = NT * 128;

  size_t off = 0;
  auto alloc = [&](size_t bytes) -> void* {
    void* p = (char*)d_ws + off;
    off += (bytes + 255) & ~(size_t)255;
    return p;
  };
  float* agg = (float*)alloc((size_t)n * DIM * 4);
  float* h1 = (float*)alloc((size_t)n * DIM * 4);
  uint4* vhi = (uint4*)alloc((size_t)P * 16);
  uint4* vlo = (uint4*)alloc((size_t)P * 16);
  uint4* hhi = (uint4*)alloc((size_t)NT * 256 * 16);
  uint4* hlo = (uint4*)alloc((size_t)NT * 256 * 16);
  int* deg = (int*)alloc((size_t)n * 4);
  int* offs = (int*)alloc((size_t)n * 4);
  int* cursor = (int*)alloc((size_t)n * 4);
  int* csr = (int*)alloc((size_t)E * 4);
  float* sc1 = (float*)alloc(TWO_DIM * 4);
  float* sh1 = (float*)alloc(TWO_DIM * 4);
  float* sc2 = (float*)alloc(TWO_DIM * 4);
  float* sh2 = (float*)alloc(TWO_DIM * 4);
  uint4* w1hA = (uint4*)alloc(1024 * 16);
  uint4* w1lA = (uint4*)alloc(1024 * 16);
  uint4* w2hA = (uint4*)alloc(1024 * 16);
  uint4* w2lA = (uint4*)alloc(1024 * 16);
  uint4* w1hB = (uint4*)alloc(1024 * 16);
  uint4* w1lB = (uint4*)alloc(1024 * 16);
  uint4* w2hB = (uint4*)alloc(1024 * 16);
  uint4* w2lB = (uint4*)alloc(1024 * 16);
  float* pooled = (float*)alloc((size_t)G * DIM * 4);
  int* cnt = (int*)alloc((size_t)G * 4);
  int* bsum = (int*)alloc(512 * 4);

  hipMemsetAsync(deg, 0, (size_t)n * 4, stream);
  hipMemsetAsync(cnt, 0, (size_t)G * 4, stream);
  hipMemsetAsync(pooled, 0, (size_t)G * DIM * 4, stream);

  const int nb = (n + 255) / 256;
  k_hist<<<1024, 256, 0, stream>>>(dst, deg, E);
  k_hist<<<256, 256, 0, stream>>>(batch, cnt, n);
  k_scan_part<<<nb, 256, 0, stream>>>(deg, bsum, n);
  k_scan_mid<<<1, 512, 0, stream>>>(bsum, nb);
  k_scan_final<<<nb, 256, 0, stream>>>(deg, bsum, offs, cursor, n);
  k_scatter<<<1024, 256, 0, stream>>>(src, dst, cursor, csr, E, n);
  k_prep<<<1, TWO_DIM, 0, stream>>>(b11, g1, be1, sc1, sh1);
  k_prep<<<1, TWO_DIM, 0, stream>>>(b21, g2, be2, sc2, sh2);
  k_prepw<<<8, 256, 0, stream>>>(W11, W12, w1hA, w1lA, w2hA, w2lA);
  k_prepw<<<8, 256, 0, stream>>>(W21, W22, w1hB, w1lB, w2hB, w2lB);

  const int gT = (NT + 3) / 4;
  // GIN layer 1
  k_gather<<<(n + 3) / 4, 256, 0, stream>>>(x, csr, offs, deg, agg, n);
  k_split<<<(P + 255) / 256, 256, 0, stream>>>(x, agg, eps1, vhi, vlo, n, P);
  k_g1<<<gT, 256, 0, stream>>>(vhi, vlo, w1hA, w1lA, sc1, sh1, hhi, hlo, NT);
  k_g2<false><<<gT, 256, 0, stream>>>(hhi, hlo, w2hA, w2lA, b12, h1, nullptr,
                                      nullptr, n, NT);
  // GIN layer 2
  k_gather<<<(n + 3) / 4, 256, 0, stream>>>(h1, csr, offs, deg, agg, n);
  k_split<<<(P + 255) / 256, 256, 0, stream>>>(h1, agg, eps2, vhi, vlo, n, P);
  k_g1<<<gT, 256, 0, stream>>>(vhi, vlo, w1hB, w1lB, sc2, sh2, hhi, hlo, NT);
  k_g2<true><<<gT, 256, 0, stream>>>(hhi, hlo, w2hB, w2lB, b22, nullptr, pooled,
                                     batch, n, NT);
  k_out<<<G, DIM, 0, stream>>>(pooled, cnt, linW, linb, (float*)d_out);
}

// Round 9
// 480.413 us; speedup vs baseline: 2.7177x; 1.2338x over previous
//
#include <hip/hip_runtime.h>

#define DIM 64
#define TWO_DIM 128

typedef __attribute__((ext_vector_type(8))) short bf16x8;
typedef __attribute__((ext_vector_type(4))) float f32x4;
#define MFMA16(A, B, C) __builtin_amdgcn_mfma_f32_16x16x32_bf16(A, B, C, 0, 0, 0)

__device__ __forceinline__ float fast_tanh(float x) {
  float cx = fminf(fmaxf(x, -15.0f), 15.0f);
  float e = __expf(2.0f * cx);
  return (e - 1.0f) / (e + 1.0f);
}

__device__ __forceinline__ unsigned short f2bf(float x) {
  unsigned int b = __float_as_uint(x);
  unsigned int r = b + 0x7FFFu + ((b >> 16) & 1u);
  return (unsigned short)(r >> 16);
}
__device__ __forceinline__ float bf2f(unsigned short h) {
  return __uint_as_float(((unsigned int)h) << 16);
}
__device__ __forceinline__ uint4 pack8(const unsigned short* s) {
  uint4 u;
  u.x = (unsigned)s[0] | ((unsigned)s[1] << 16);
  u.y = (unsigned)s[2] | ((unsigned)s[3] << 16);
  u.z = (unsigned)s[4] | ((unsigned)s[5] << 16);
  u.w = (unsigned)s[6] | ((unsigned)s[7] << 16);
  return u;
}

// ---------------- graph machinery ----------------
// Dst-range-partitioned histogram: blocks with (blockIdx&7)==r count only
// dst values in node-range r, so each deg cacheline is atomically updated
// from a single XCD's L2 (kills cross-XCD line ping-pong).
__global__ void k_hist_dst(const int* __restrict__ dst, int* __restrict__ cnt,
                           int E, int n) {
  const int r = blockIdx.x & 7;
  const int sub = blockIdx.x >> 3;
  const int nsub = gridDim.x >> 3;
  const int span = (n + 7) >> 3;
  const int lo = r * span;
  const int hi = min(n, lo + span);

  int tid = sub * blockDim.x + threadIdx.x;
  int stride = nsub * blockDim.x;
  int E4 = E >> 2;
  const int4* p = reinterpret_cast<const int4*>(dst);
  for (int i = tid; i < E4; i += stride) {
    int4 v = p[i];
    if (v.x >= lo && v.x < hi) atomicAdd(&cnt[v.x], 1);
    if (v.y >= lo && v.y < hi) atomicAdd(&cnt[v.y], 1);
    if (v.z >= lo && v.z < hi) atomicAdd(&cnt[v.z], 1);
    if (v.w >= lo && v.w < hi) atomicAdd(&cnt[v.w], 1);
  }
  if (blockIdx.x == 0 && threadIdx.x == 0) {
    for (int i = E4 << 2; i < E; ++i) atomicAdd(&cnt[dst[i]], 1);
  }
}

// LDS-privatized 256-bin histogram (for the batch -> graph counts).
__global__ void k_hist256(const int* __restrict__ idx, int* __restrict__ cnt,
                          int n) {
  __shared__ int h[256];
  int t = threadIdx.x;
  h[t] = 0;
  __syncthreads();
  int tid = blockIdx.x * blockDim.x + t;
  int stride = gridDim.x * blockDim.x;
  int n4 = n >> 2;
  const int4* p = reinterpret_cast<const int4*>(idx);
  for (int i = tid; i < n4; i += stride) {
    int4 v = p[i];
    atomicAdd(&h[v.x & 255], 1);
    atomicAdd(&h[v.y & 255], 1);
    atomicAdd(&h[v.z & 255], 1);
    atomicAdd(&h[v.w & 255], 1);
  }
  if (tid == 0) {
    for (int i = n4 << 2; i < n; ++i) atomicAdd(&cnt[idx[i]], 1);
  }
  __syncthreads();
  if (h[t] > 0) atomicAdd(&cnt[t], h[t]);
}

__global__ void k_scan_part(const int* __restrict__ deg, int* __restrict__ bsum,
                            int n) {
  __shared__ int red[256];
  int t = threadIdx.x;
  int i = blockIdx.x * 256 + t;
  red[t] = (i < n) ? deg[i] : 0;
  __syncthreads();
#pragma unroll
  for (int off = 128; off >= 1; off >>= 1) {
    if (t < off) red[t] += red[t + off];
    __syncthreads();
  }
  if (t == 0) bsum[blockIdx.x] = red[0];
}

__global__ void k_scan_mid(int* __restrict__ bsum, int nb) {
  __shared__ int s[512];
  int t = threadIdx.x;
  int v = (t < nb) ? bsum[t] : 0;
  s[t] = v;
  __syncthreads();
#pragma unroll
  for (int off = 1; off < 512; off <<= 1) {
    int u = (t >= off) ? s[t - off] : 0;
    __syncthreads();
    s[t] += u;
    __syncthreads();
  }
  if (t < nb) bsum[t] = s[t] - v;
}

__global__ void k_scan_final(const int* __restrict__ deg, const int* __restrict__ bsum,
                             int* __restrict__ offs, int* __restrict__ cursor, int n) {
  __shared__ int s[256];
  int t = threadIdx.x;
  int i = blockIdx.x * 256 + t;
  int d = (i < n) ? deg[i] : 0;
  s[t] = d;
  __syncthreads();
#pragma unroll
  for (int off = 1; off < 256; off <<= 1) {
    int u = (t >= off) ? s[t - off] : 0;
    __syncthreads();
    s[t] += u;
    __syncthreads();
  }
  int ex = bsum[blockIdx.x] + s[t] - d;
  if (i < n) {
    offs[i] = ex;
    cursor[i] = ex;
  }
}

// Dst-range-partitioned scatter (round-8, kept).
__global__ void k_scatter(const int* __restrict__ src, const int* __restrict__ dst,
                          int* __restrict__ cursor, int* __restrict__ csr, int E,
                          int n) {
  const int r = blockIdx.x & 7;
  const int sub = blockIdx.x >> 3;
  const int nsub = gridDim.x >> 3;
  const int span = (n + 7) >> 3;
  const int lo = r * span;
  const int hi = min(n, lo + span);

  int tid = sub * blockDim.x + threadIdx.x;
  int stride = nsub * blockDim.x;
  int E4 = E >> 2;
  const int4* s4 = reinterpret_cast<const int4*>(src);
  const int4* d4 = reinterpret_cast<const int4*>(dst);
  for (int i = tid; i < E4; i += stride) {
    int4 d = d4[i];
    bool a0 = (d.x >= lo) & (d.x < hi);
    bool a1 = (d.y >= lo) & (d.y < hi);
    bool a2 = (d.z >= lo) & (d.z < hi);
    bool a3 = (d.w >= lo) & (d.w < hi);
    if (a0 | a1 | a2 | a3) {
      int4 s = s4[i];
      if (a0) { int p = atomicAdd(&cursor[d.x], 1); csr[p] = s.x; }
      if (a1) { int p = atomicAdd(&cursor[d.y], 1); csr[p] = s.y; }
      if (a2) { int p = atomicAdd(&cursor[d.z], 1); csr[p] = s.z; }
      if (a3) { int p = atomicAdd(&cursor[d.w], 1); csr[p] = s.w; }
    }
  }
  if (blockIdx.x == 0 && threadIdx.x == 0) {
    for (int i = E4 << 2; i < E; ++i) {
      int p = atomicAdd(&cursor[dst[i]], 1);
      csr[p] = src[i];
    }
  }
}

// one 64-lane wave per node; lane = feature
__global__ void k_gather(const float* __restrict__ x, const int* __restrict__ csr,
                         const int* __restrict__ offs, const int* __restrict__ deg,
                         float* __restrict__ agg, int n) {
  int node = blockIdx.x * 4 + (threadIdx.x >> 6);
  int t = threadIdx.x & 63;
  if (node >= n) return;
  int s = offs[node], d = deg[node];
  float acc = 0.0f;
  for (int base = 0; base < d; base += 64) {
    int m = min(64, d - base);
    int myi = (t < m) ? csr[s + base + t] : 0;
    for (int i = 0; i < m; ++i) {
      int sn = __shfl(myi, i);
      acc += x[(size_t)sn * DIM + t];
    }
  }
  agg[(size_t)node * DIM + t] = acc;
}

// fold BN(eval) into scale/shift
__global__ void k_prep(const float* __restrict__ b1, const float* __restrict__ gamma,
                       const float* __restrict__ beta, float* __restrict__ sc,
                       float* __restrict__ sh) {
  int i = threadIdx.x;
  if (i < TWO_DIM) {
    float s = gamma[i] * rsqrtf(1.0f + 1e-5f);
    sc[i] = s;
    sh[i] = b1[i] * s + beta[i];
  }
}

// Pack W1 [64][128] and W2 [128][64] into MFMA B-fragment order, hi/lo bf16 split.
__global__ void k_prepw(const float* __restrict__ W1, const float* __restrict__ W2,
                        uint4* __restrict__ w1h, uint4* __restrict__ w1l,
                        uint4* __restrict__ w2h, uint4* __restrict__ w2l) {
  int p = blockIdx.x * 256 + threadIdx.x;  // 0..2047
  if (p >= 2048) return;
  int lane = p & 63;
  int c = lane & 15, g = lane >> 4;
  unsigned short hh[8], ll[8];
  if (p < 1024) {
    int nt = p >> 7, f = (p >> 6) & 1;
    int nn = nt * 16 + c, kb = f * 32 + g * 8;
#pragma unroll
    for (int e = 0; e < 8; ++e) {
      float w = W1[(kb + e) * TWO_DIM + nn];
      hh[e] = f2bf(w);
      ll[e] = f2bf(w - bf2f(hh[e]));
    }
    w1h[p] = pack8(hh);
    w1l[p] = pack8(ll);
  } else {
    int q = p - 1024;
    int nt = q >> 8, f = (q >> 6) & 3;
    int nn = nt * 16 + c, kb = f * 32 + g * 8;
#pragma unroll
    for (int e = 0; e < 8; ++e) {
      float w = W2[(kb + e) * DIM + nn];
      hh[e] = f2bf(w);
      ll[e] = f2bf(w - bf2f(hh[e]));
    }
    w2h[q] = pack8(hh);
    w2l[q] = pack8(ll);
  }
}

// v = (1+eps)*x + agg, split hi/lo bf16, packed in MFMA A-frag order.
__global__ void k_split(const float* __restrict__ xin, const float* __restrict__ agg,
                        const float* __restrict__ epsp, uint4* __restrict__ vh,
                        uint4* __restrict__ vl, int n, int P) {
  int p = blockIdx.x * 256 + threadIdx.x;
  if (p >= P) return;
  float ep = 1.0f + epsp[0];
  int lane = p & 63;
  int T = p >> 7;
  int f = (p >> 6) & 1;
  int m = T * 16 + (lane & 15);
  int k0 = f * 32 + (lane >> 4) * 8;
  float v[8];
  if (m < n) {
    const float4* xa = reinterpret_cast<const float4*>(xin + (size_t)m * DIM + k0);
    const float4* aa = reinterpret_cast<const float4*>(agg + (size_t)m * DIM + k0);
    float4 x0 = xa[0], x1 = xa[1], a0 = aa[0], a1 = aa[1];
    v[0] = ep * x0.x + a0.x; v[1] = ep * x0.y + a0.y;
    v[2] = ep * x0.z + a0.z; v[3] = ep * x0.w + a0.w;
    v[4] = ep * x1.x + a1.x; v[5] = ep * x1.y + a1.y;
    v[6] = ep * x1.z + a1.z; v[7] = ep * x1.w + a1.w;
  } else {
#pragma unroll
    for (int e = 0; e < 8; ++e) v[e] = 0.0f;
  }
  unsigned short hh[8], ll[8];
#pragma unroll
  for (int e = 0; e < 8; ++e) {
    hh[e] = f2bf(v[e]);
    ll[e] = f2bf(v[e] - bf2f(hh[e]));
  }
  vh[p] = pack8(hh);
  vl[p] = pack8(ll);
}

// GEMM1 + BN + tanh + split + repack for GEMM2.
__launch_bounds__(256, 2)
__global__ void k_g1(const uint4* __restrict__ vh, const uint4* __restrict__ vl,
                     const uint4* __restrict__ w1h, const uint4* __restrict__ w1l,
                     const float* __restrict__ sc, const float* __restrict__ sh,
                     uint4* __restrict__ hh, uint4* __restrict__ hl, int NTiles) {
  __shared__ uint4 sBh[1024], sBl[1024];
  __shared__ float ssc[TWO_DIM], ssh[TWO_DIM];
  __shared__ float sH[4 * 16 * 132];

  int t = threadIdx.x;
#pragma unroll
  for (int q = 0; q < 4; ++q) {
    sBh[q * 256 + t] = w1h[q * 256 + t];
    sBl[q * 256 + t] = w1l[q * 256 + t];
  }
  if (t < TWO_DIM) {
    ssc[t] = sc[t];
    ssh[t] = sh[t];
  }
  __syncthreads();

  const int wid = t >> 6, lane = t & 63;
  const int T = blockIdx.x * 4 + wid;
  if (T >= NTiles) return;
  const int c = lane & 15, g = lane >> 4;

  const bf16x8* Ah = reinterpret_cast<const bf16x8*>(vh + (size_t)T * 128);
  const bf16x8* Al = reinterpret_cast<const bf16x8*>(vl + (size_t)T * 128);
  bf16x8 ah0 = Ah[lane], ah1 = Ah[64 + lane];
  bf16x8 al0 = Al[lane], al1 = Al[64 + lane];

  const bf16x8* Bh = reinterpret_cast<const bf16x8*>(sBh);
  const bf16x8* Bl = reinterpret_cast<const bf16x8*>(sBl);
  float* myH = sH + wid * (16 * 132);

#pragma unroll
  for (int nt = 0; nt < 8; ++nt) {
    f32x4 acc = {0.f, 0.f, 0.f, 0.f};
    bf16x8 bh0 = Bh[(nt * 2 + 0) * 64 + lane];
    bf16x8 bl0 = Bl[(nt * 2 + 0) * 64 + lane];
    bf16x8 bh1 = Bh[(nt * 2 + 1) * 64 + lane];
    bf16x8 bl1 = Bl[(nt * 2 + 1) * 64 + lane];
    acc = MFMA16(ah0, bh0, acc);
    acc = MFMA16(ah1, bh1, acc);
    acc = MFMA16(ah0, bl0, acc);
    acc = MFMA16(ah1, bl1, acc);
    acc = MFMA16(al0, bh0, acc);
    acc = MFMA16(al1, bh1, acc);
    int j = nt * 16 + c;
    float scj = ssc[j], shj = ssh[j];
#pragma unroll
    for (int r = 0; r < 4; ++r)
      myH[(g * 4 + r) * 132 + j] = fast_tanh(acc[r] * scj + shj);
  }

#pragma unroll
  for (int f2 = 0; f2 < 4; ++f2) {
    const float* hp = myH + c * 132 + f2 * 32 + g * 8;
    float4 v0 = *reinterpret_cast<const float4*>(hp);
    float4 v1 = *reinterpret_cast<const float4*>(hp + 4);
    float vv[8] = {v0.x, v0.y, v0.z, v0.w, v1.x, v1.y, v1.z, v1.w};
    unsigned short H[8], L[8];
#pragma unroll
    for (int e = 0; e < 8; ++e) {
      H[e] = f2bf(vv[e]);
      L[e] = f2bf(vv[e] - bf2f(H[e]));
    }
    size_t o = ((size_t)T * 4 + f2) * 64 + lane;
    hh[o] = pack8(H);
    hl[o] = pack8(L);
  }
}

// GEMM2 + tanh (+pool). C = H[16x128] @ W2[128x64].
template <bool POOL>
__launch_bounds__(256, 2)
__global__ void k_g2(const uint4* __restrict__ hh, const uint4* __restrict__ hl,
                     const uint4* __restrict__ w2h, const uint4* __restrict__ w2l,
                     const float* __restrict__ b2, float* __restrict__ hout,
                     float* __restrict__ pooled, const int* __restrict__ batch,
                     int n, int NTiles) {
  __shared__ uint4 sBh[1024], sBl[1024];
  __shared__ float sb2[DIM];

  int t = threadIdx.x;
#pragma unroll
  for (int q = 0; q < 4; ++q) {
    sBh[q * 256 + t] = w2h[q * 256 + t];
    sBl[q * 256 + t] = w2l[q * 256 + t];
  }
  if (t < DIM) sb2[t] = b2[t];
  __syncthreads();

  const int wid = t >> 6, lane = t & 63;
  const int T = blockIdx.x * 4 + wid;
  if (T >= NTiles) return;
  const int c = lane & 15, g = lane >> 4;

  const bf16x8* Ah = reinterpret_cast<const bf16x8*>(hh + (size_t)T * 256);
  const bf16x8* Al = reinterpret_cast<const bf16x8*>(hl + (size_t)T * 256);
  bf16x8 ah0 = Ah[lane], ah1 = Ah[64 + lane], ah2 = Ah[128 + lane], ah3 = Ah[192 + lane];
  bf16x8 al0 = Al[lane], al1 = Al[64 + lane], al2 = Al[128 + lane], al3 = Al[192 + lane];

  const bf16x8* Bh = reinterpret_cast<const bf16x8*>(sBh);
  const bf16x8* Bl = reinterpret_cast<const bf16x8*>(sBl);

  bool uni = false;
  int b0 = 0;
  if (POOL) {
    b0 = batch[min(T * 16, n - 1)];
    int b15 = batch[min(T * 16 + 15, n - 1)];
    uni = (b0 == b15) && (T * 16 + 15 < n);
  }

#pragma unroll
  for (int nt = 0; nt < 4; ++nt) {
    f32x4 acc = {0.f, 0.f, 0.f, 0.f};
    bf16x8 bh0 = Bh[(nt * 4 + 0) * 64 + lane];
    bf16x8 bh1 = Bh[(nt * 4 + 1) * 64 + lane];
    bf16x8 bh2 = Bh[(nt * 4 + 2) * 64 + lane];
    bf16x8 bh3 = Bh[(nt * 4 + 3) * 64 + lane];
    bf16x8 bl0 = Bl[(nt * 4 + 0) * 64 + lane];
    bf16x8 bl1 = Bl[(nt * 4 + 1) * 64 + lane];
    bf16x8 bl2 = Bl[(nt * 4 + 2) * 64 + lane];
    bf16x8 bl3 = Bl[(nt * 4 + 3) * 64 + lane];
    acc = MFMA16(ah0, bh0, acc);
    acc = MFMA16(ah1, bh1, acc);
    acc = MFMA16(ah2, bh2, acc);
    acc = MFMA16(ah3, bh3, acc);
    acc = MFMA16(ah0, bl0, acc);
    acc = MFMA16(ah1, bl1, acc);
    acc = MFMA16(ah2, bl2, acc);
    acc = MFMA16(ah3, bl3, acc);
    acc = MFMA16(al0, bh0, acc);
    acc = MFMA16(al1, bh1, acc);
    acc = MFMA16(al2, bh2, acc);
    acc = MFMA16(al3, bh3, acc);

    int j = nt * 16 + c;
    float bj = sb2[j];
    float o0 = fast_tanh(acc[0] + bj);
    float o1 = fast_tanh(acc[1] + bj);
    float o2 = fast_tanh(acc[2] + bj);
    float o3 = fast_tanh(acc[3] + bj);
    if (POOL) {
      if (uni) {
        float os = (o0 + o1) + (o2 + o3);
        os += __shfl_xor(os, 16);
        os += __shfl_xor(os, 32);
        if (g == 0) atomicAdd(&pooled[(size_t)b0 * DIM + j], os);
      } else {
        int mb = T * 16 + g * 4;
#pragma unroll
        for (int r = 0; r < 4; ++r) {
          int m = mb + r;
          float o = (r == 0) ? o0 : (r == 1) ? o1 : (r == 2) ? o2 : o3;
          if (m < n) atomicAdd(&pooled[(size_t)batch[m] * DIM + j], o);
        }
      }
    } else {
      int mb = T * 16 + g * 4;
      if (mb + 0 < n) hout[(size_t)(mb + 0) * DIM + j] = o0;
      if (mb + 1 < n) hout[(size_t)(mb + 1) * DIM + j] = o1;
      if (mb + 2 < n) hout[(size_t)(mb + 2) * DIM + j] = o2;
      if (mb + 3 < n) hout[(size_t)(mb + 3) * DIM + j] = o3;
    }
  }
}

// out[g][i] = tanh( (pooled[g]/max(cnt,1)) . linW[:,i] + linb[i] )
__global__ void k_out(const float* __restrict__ pooled, const int* __restrict__ cnt,
                      const float* __restrict__ linW, const float* __restrict__ linb,
                      float* __restrict__ out) {
  int g = blockIdx.x;
  int i = threadIdx.x;
  int c = cnt[g];
  float inv = 1.0f / (float)(c > 0 ? c : 1);
  float acc = 0.0f;
#pragma unroll
  for (int k = 0; k < DIM; ++k)
    acc += pooled[(size_t)g * DIM + k] * linW[k * DIM + i];
  out[(size_t)g * DIM + i] = fast_tanh(acc * inv + linb[i]);
}

extern "C" void kernel_launch(void* const* d_in, const int* in_sizes, int n_in,
                              void* d_out, int out_size, void* d_ws, size_t ws_size,
                              hipStream_t stream) {
  const float* x = (const float*)d_in[0];
  const int* ei = (const int*)d_in[1];
  const int* batch = (const int*)d_in[2];
  const float* eps1 = (const float*)d_in[3];
  const float* W11 = (const float*)d_in[4];
  const float* b11 = (const float*)d_in[5];
  const float* g1 = (const float*)d_in[6];
  const float* be1 = (const float*)d_in[7];
  const float* W12 = (const float*)d_in[8];
  const float* b12 = (const float*)d_in[9];
  const float* eps2 = (const float*)d_in[10];
  const float* W21 = (const float*)d_in[11];
  const float* b21 = (const float*)d_in[12];
  const float* g2 = (const float*)d_in[13];
  const float* be2 = (const float*)d_in[14];
  const float* W22 = (const float*)d_in[15];
  const float* b22 = (const float*)d_in[16];
  const float* linW = (const float*)d_in[17];
  const float* linb = (const float*)d_in[18];

  const int n = in_sizes[0] / DIM;  // 100000
  const int E = in_sizes[1] / 2;    // 1600000
  const int G = out_size / DIM;     // 256
  const int* src = ei;
  const int* dst = ei + E;
  const int NT = (n + 15) / 16;     // 6250
  const int P = NT * 128;

  size_t off = 0;
  auto alloc = [&](size_t bytes) -> void* {
    void* p = (char*)d_ws + off;
    off += (bytes + 255) & ~(size_t)255;
    return p;
  };
  float* agg = (float*)alloc((size_t)n * DIM * 4);
  float* h1 = (float*)alloc((size_t)n * DIM * 4);
  uint4* vhi = (uint4*)alloc((size_t)P * 16);
  uint4* vlo = (uint4*)alloc((size_t)P * 16);
  uint4* hhi = (uint4*)alloc((size_t)NT * 256 * 16);
  uint4* hlo = (uint4*)alloc((size_t)NT * 256 * 16);
  int* deg = (int*)alloc((size_t)n * 4);
  int* offs = (int*)alloc((size_t)n * 4);
  int* cursor = (int*)alloc((size_t)n * 4);
  int* csr = (int*)alloc((size_t)E * 4);
  float* sc1 = (float*)alloc(TWO_DIM * 4);
  float* sh1 = (float*)alloc(TWO_DIM * 4);
  float* sc2 = (float*)alloc(TWO_DIM * 4);
  float* sh2 = (float*)alloc(TWO_DIM * 4);
  uint4* w1hA = (uint4*)alloc(1024 * 16);
  uint4* w1lA = (uint4*)alloc(1024 * 16);
  uint4* w2hA = (uint4*)alloc(1024 * 16);
  uint4* w2lA = (uint4*)alloc(1024 * 16);
  uint4* w1hB = (uint4*)alloc(1024 * 16);
  uint4* w1lB = (uint4*)alloc(1024 * 16);
  uint4* w2hB = (uint4*)alloc(1024 * 16);
  uint4* w2lB = (uint4*)alloc(1024 * 16);
  float* pooled = (float*)alloc((size_t)G * DIM * 4);
  int* cnt = (int*)alloc((size_t)G * 4);
  int* bsum = (int*)alloc(512 * 4);

  hipMemsetAsync(deg, 0, (size_t)n * 4, stream);
  hipMemsetAsync(cnt, 0, (size_t)G * 4, stream);
  hipMemsetAsync(pooled, 0, (size_t)G * DIM * 4, stream);

  const int nb = (n + 255) / 256;
  k_hist_dst<<<1024, 256, 0, stream>>>(dst, deg, E, n);
  k_hist256<<<64, 256, 0, stream>>>(batch, cnt, n);
  k_scan_part<<<nb, 256, 0, stream>>>(deg, bsum, n);
  k_scan_mid<<<1, 512, 0, stream>>>(bsum, nb);
  k_scan_final<<<nb, 256, 0, stream>>>(deg, bsum, offs, cursor, n);
  k_scatter<<<1024, 256, 0, stream>>>(src, dst, cursor, csr, E, n);
  k_prep<<<1, TWO_DIM, 0, stream>>>(b11, g1, be1, sc1, sh1);
  k_prep<<<1, TWO_DIM, 0, stream>>>(b21, g2, be2, sc2, sh2);
  k_prepw<<<8, 256, 0, stream>>>(W11, W12, w1hA, w1lA, w2hA, w2lA);
  k_prepw<<<8, 256, 0, stream>>>(W21, W22, w1hB, w1lB, w2hB, w2lB);

  const int gT = (NT + 3) / 4;
  // GIN layer 1
  k_gather<<<(n + 3) / 4, 256, 0, stream>>>(x, csr, offs, deg, agg, n);
  k_split<<<(P + 255) / 256, 256, 0, stream>>>(x, agg, eps1, vhi, vlo, n, P);
  k_g1<<<gT, 256, 0, stream>>>(vhi, vlo, w1hA, w1lA, sc1, sh1, hhi, hlo, NT);
  k_g2<false><<<gT, 256, 0, stream>>>(hhi, hlo, w2hA, w2lA, b12, h1, nullptr,
                                      nullptr, n, NT);
  // GIN layer 2
  k_gather<<<(n + 3) / 4, 256, 0, stream>>>(h1, csr, offs, deg, agg, n);
  k_split<<<(P + 255) / 256, 256, 0, stream>>>(h1, agg, eps2, vhi, vlo, n, P);
  k_g1<<<gT, 256, 0, stream>>>(vhi, vlo, w1hB, w1lB, sc2, sh2, hhi, hlo, NT);
  k_g2<true><<<gT, 256, 0, stream>>>(hhi, hlo, w2hB, w2lB, b22, nullptr, pooled,
                                     batch, n, NT);
  k_out<<<G, DIM, 0, stream>>>(pooled, cnt, linW, linb, (float*)d_out);
}

// Round 10
// 390.154 us; speedup vs baseline: 3.3464x; 1.2313x over previous
//
#include <hip/hip_runtime.h>

#define DIM 64
#define TWO_DIM 128

typedef __attribute__((ext_vector_type(8))) short bf16x8;
typedef __attribute__((ext_vector_type(4))) float f32x4;
#define MFMA16(A, B, C) __builtin_amdgcn_mfma_f32_16x16x32_bf16(A, B, C, 0, 0, 0)

__device__ __forceinline__ float fast_tanh(float x) {
  float cx = fminf(fmaxf(x, -15.0f), 15.0f);
  float e = __expf(2.0f * cx);
  return (e - 1.0f) / (e + 1.0f);
}

__device__ __forceinline__ unsigned short f2bf(float x) {
  unsigned int b = __float_as_uint(x);
  unsigned int r = b + 0x7FFFu + ((b >> 16) & 1u);
  return (unsigned short)(r >> 16);
}
__device__ __forceinline__ float bf2f(unsigned short h) {
  return __uint_as_float(((unsigned int)h) << 16);
}
__device__ __forceinline__ uint4 pack8(const unsigned short* s) {
  uint4 u;
  u.x = (unsigned)s[0] | ((unsigned)s[1] << 16);
  u.y = (unsigned)s[2] | ((unsigned)s[3] << 16);
  u.z = (unsigned)s[4] | ((unsigned)s[5] << 16);
  u.w = (unsigned)s[6] | ((unsigned)s[7] << 16);
  return u;
}

// ---------------- graph machinery ----------------
// Dst-range-partitioned histogram (round-9, kept).
__global__ void k_hist_dst(const int* __restrict__ dst, int* __restrict__ cnt,
                           int E, int n) {
  const int r = blockIdx.x & 7;
  const int sub = blockIdx.x >> 3;
  const int nsub = gridDim.x >> 3;
  const int span = (n + 7) >> 3;
  const int lo = r * span;
  const int hi = min(n, lo + span);

  int tid = sub * blockDim.x + threadIdx.x;
  int stride = nsub * blockDim.x;
  int E4 = E >> 2;
  const int4* p = reinterpret_cast<const int4*>(dst);
  for (int i = tid; i < E4; i += stride) {
    int4 v = p[i];
    if (v.x >= lo && v.x < hi) atomicAdd(&cnt[v.x], 1);
    if (v.y >= lo && v.y < hi) atomicAdd(&cnt[v.y], 1);
    if (v.z >= lo && v.z < hi) atomicAdd(&cnt[v.z], 1);
    if (v.w >= lo && v.w < hi) atomicAdd(&cnt[v.w], 1);
  }
  if (blockIdx.x == 0 && threadIdx.x == 0) {
    for (int i = E4 << 2; i < E; ++i) atomicAdd(&cnt[dst[i]], 1);
  }
}

// LDS-privatized 256-bin histogram (for the batch -> graph counts).
__global__ void k_hist256(const int* __restrict__ idx, int* __restrict__ cnt,
                          int n) {
  __shared__ int h[256];
  int t = threadIdx.x;
  h[t] = 0;
  __syncthreads();
  int tid = blockIdx.x * blockDim.x + t;
  int stride = gridDim.x * blockDim.x;
  int n4 = n >> 2;
  const int4* p = reinterpret_cast<const int4*>(idx);
  for (int i = tid; i < n4; i += stride) {
    int4 v = p[i];
    atomicAdd(&h[v.x & 255], 1);
    atomicAdd(&h[v.y & 255], 1);
    atomicAdd(&h[v.z & 255], 1);
    atomicAdd(&h[v.w & 255], 1);
  }
  if (tid == 0) {
    for (int i = n4 << 2; i < n; ++i) atomicAdd(&cnt[idx[i]], 1);
  }
  __syncthreads();
  if (h[t] > 0) atomicAdd(&cnt[t], h[t]);
}

__global__ void k_scan_part(const int* __restrict__ deg, int* __restrict__ bsum,
                            int n) {
  __shared__ int red[256];
  int t = threadIdx.x;
  int i = blockIdx.x * 256 + t;
  red[t] = (i < n) ? deg[i] : 0;
  __syncthreads();
#pragma unroll
  for (int off = 128; off >= 1; off >>= 1) {
    if (t < off) red[t] += red[t + off];
    __syncthreads();
  }
  if (t == 0) bsum[blockIdx.x] = red[0];
}

__global__ void k_scan_mid(int* __restrict__ bsum, int nb) {
  __shared__ int s[512];
  int t = threadIdx.x;
  int v = (t < nb) ? bsum[t] : 0;
  s[t] = v;
  __syncthreads();
#pragma unroll
  for (int off = 1; off < 512; off <<= 1) {
    int u = (t >= off) ? s[t - off] : 0;
    __syncthreads();
    s[t] += u;
    __syncthreads();
  }
  if (t < nb) bsum[t] = s[t] - v;
}

__global__ void k_scan_final(const int* __restrict__ deg, const int* __restrict__ bsum,
                             int* __restrict__ offs, int* __restrict__ cursor, int n) {
  __shared__ int s[256];
  int t = threadIdx.x;
  int i = blockIdx.x * 256 + t;
  int d = (i < n) ? deg[i] : 0;
  s[t] = d;
  __syncthreads();
#pragma unroll
  for (int off = 1; off < 256; off <<= 1) {
    int u = (t >= off) ? s[t - off] : 0;
    __syncthreads();
    s[t] += u;
    __syncthreads();
  }
  int ex = bsum[blockIdx.x] + s[t] - d;
  if (i < n) {
    offs[i] = ex;
    cursor[i] = ex;
  }
}

// Dst-range-partitioned scatter (round-8, kept).
__global__ void k_scatter(const int* __restrict__ src, const int* __restrict__ dst,
                          int* __restrict__ cursor, int* __restrict__ csr, int E,
                          int n) {
  const int r = blockIdx.x & 7;
  const int sub = blockIdx.x >> 3;
  const int nsub = gridDim.x >> 3;
  const int span = (n + 7) >> 3;
  const int lo = r * span;
  const int hi = min(n, lo + span);

  int tid = sub * blockDim.x + threadIdx.x;
  int stride = nsub * blockDim.x;
  int E4 = E >> 2;
  const int4* s4 = reinterpret_cast<const int4*>(src);
  const int4* d4 = reinterpret_cast<const int4*>(dst);
  for (int i = tid; i < E4; i += stride) {
    int4 d = d4[i];
    bool a0 = (d.x >= lo) & (d.x < hi);
    bool a1 = (d.y >= lo) & (d.y < hi);
    bool a2 = (d.z >= lo) & (d.z < hi);
    bool a3 = (d.w >= lo) & (d.w < hi);
    if (a0 | a1 | a2 | a3) {
      int4 s = s4[i];
      if (a0) { int p = atomicAdd(&cursor[d.x], 1); csr[p] = s.x; }
      if (a1) { int p = atomicAdd(&cursor[d.y], 1); csr[p] = s.y; }
      if (a2) { int p = atomicAdd(&cursor[d.z], 1); csr[p] = s.z; }
      if (a3) { int p = atomicAdd(&cursor[d.w], 1); csr[p] = s.w; }
    }
  }
  if (blockIdx.x == 0 && threadIdx.x == 0) {
    for (int i = E4 << 2; i < E; ++i) {
      int p = atomicAdd(&cursor[dst[i]], 1);
      csr[p] = src[i];
    }
  }
}

// one 64-lane wave per node; lane = feature. 8-wide unrolled edge loop with
// 8 independent accumulators -> ~8 L2 misses in flight per wave (was 1).
__global__ void k_gather(const float* __restrict__ x, const int* __restrict__ csr,
                         const int* __restrict__ offs, const int* __restrict__ deg,
                         float* __restrict__ agg, int n) {
  int node = blockIdx.x * 4 + (threadIdx.x >> 6);
  int t = threadIdx.x & 63;
  if (node >= n) return;
  int s = offs[node], d = deg[node];
  float a0 = 0.f, a1 = 0.f, a2 = 0.f, a3 = 0.f;
  float a4 = 0.f, a5 = 0.f, a6 = 0.f, a7 = 0.f;
  for (int base = 0; base < d; base += 64) {
    int m = min(64, d - base);
    int myi = (t < m) ? csr[s + base + t] : 0;
    int i = 0;
    for (; i + 8 <= m; i += 8) {
      int s0 = __shfl(myi, i + 0);
      int s1 = __shfl(myi, i + 1);
      int s2 = __shfl(myi, i + 2);
      int s3 = __shfl(myi, i + 3);
      int s4 = __shfl(myi, i + 4);
      int s5 = __shfl(myi, i + 5);
      int s6 = __shfl(myi, i + 6);
      int s7 = __shfl(myi, i + 7);
      float v0 = x[(size_t)s0 * DIM + t];
      float v1 = x[(size_t)s1 * DIM + t];
      float v2 = x[(size_t)s2 * DIM + t];
      float v3 = x[(size_t)s3 * DIM + t];
      float v4 = x[(size_t)s4 * DIM + t];
      float v5 = x[(size_t)s5 * DIM + t];
      float v6 = x[(size_t)s6 * DIM + t];
      float v7 = x[(size_t)s7 * DIM + t];
      a0 += v0; a1 += v1; a2 += v2; a3 += v3;
      a4 += v4; a5 += v5; a6 += v6; a7 += v7;
    }
    if (i + 4 <= m) {
      int s0 = __shfl(myi, i + 0);
      int s1 = __shfl(myi, i + 1);
      int s2 = __shfl(myi, i + 2);
      int s3 = __shfl(myi, i + 3);
      float v0 = x[(size_t)s0 * DIM + t];
      float v1 = x[(size_t)s1 * DIM + t];
      float v2 = x[(size_t)s2 * DIM + t];
      float v3 = x[(size_t)s3 * DIM + t];
      a0 += v0; a1 += v1; a2 += v2; a3 += v3;
      i += 4;
    }
    for (; i < m; ++i) {
      int sn = __shfl(myi, i);
      a0 += x[(size_t)sn * DIM + t];
    }
  }
  agg[(size_t)node * DIM + t] = ((a0 + a1) + (a2 + a3)) + ((a4 + a5) + (a6 + a7));
}

// fold BN(eval) into scale/shift
__global__ void k_prep(const float* __restrict__ b1, const float* __restrict__ gamma,
                       const float* __restrict__ beta, float* __restrict__ sc,
                       float* __restrict__ sh) {
  int i = threadIdx.x;
  if (i < TWO_DIM) {
    float s = gamma[i] * rsqrtf(1.0f + 1e-5f);
    sc[i] = s;
    sh[i] = b1[i] * s + beta[i];
  }
}

// Pack W1 [64][128] and W2 [128][64] into MFMA B-fragment order, hi/lo bf16 split.
__global__ void k_prepw(const float* __restrict__ W1, const float* __restrict__ W2,
                        uint4* __restrict__ w1h, uint4* __restrict__ w1l,
                        uint4* __restrict__ w2h, uint4* __restrict__ w2l) {
  int p = blockIdx.x * 256 + threadIdx.x;  // 0..2047
  if (p >= 2048) return;
  int lane = p & 63;
  int c = lane & 15, g = lane >> 4;
  unsigned short hh[8], ll[8];
  if (p < 1024) {
    int nt = p >> 7, f = (p >> 6) & 1;
    int nn = nt * 16 + c, kb = f * 32 + g * 8;
#pragma unroll
    for (int e = 0; e < 8; ++e) {
      float w = W1[(kb + e) * TWO_DIM + nn];
      hh[e] = f2bf(w);
      ll[e] = f2bf(w - bf2f(hh[e]));
    }
    w1h[p] = pack8(hh);
    w1l[p] = pack8(ll);
  } else {
    int q = p - 1024;
    int nt = q >> 8, f = (q >> 6) & 3;
    int nn = nt * 16 + c, kb = f * 32 + g * 8;
#pragma unroll
    for (int e = 0; e < 8; ++e) {
      float w = W2[(kb + e) * DIM + nn];
      hh[e] = f2bf(w);
      ll[e] = f2bf(w - bf2f(hh[e]));
    }
    w2h[q] = pack8(hh);
    w2l[q] = pack8(ll);
  }
}

// v = (1+eps)*x + agg, split hi/lo bf16, packed in MFMA A-frag order.
__global__ void k_split(const float* __restrict__ xin, const float* __restrict__ agg,
                        const float* __restrict__ epsp, uint4* __restrict__ vh,
                        uint4* __restrict__ vl, int n, int P) {
  int p = blockIdx.x * 256 + threadIdx.x;
  if (p >= P) return;
  float ep = 1.0f + epsp[0];
  int lane = p & 63;
  int T = p >> 7;
  int f = (p >> 6) & 1;
  int m = T * 16 + (lane & 15);
  int k0 = f * 32 + (lane >> 4) * 8;
  float v[8];
  if (m < n) {
    const float4* xa = reinterpret_cast<const float4*>(xin + (size_t)m * DIM + k0);
    const float4* aa = reinterpret_cast<const float4*>(agg + (size_t)m * DIM + k0);
    float4 x0 = xa[0], x1 = xa[1], a0 = aa[0], a1 = aa[1];
    v[0] = ep * x0.x + a0.x; v[1] = ep * x0.y + a0.y;
    v[2] = ep * x0.z + a0.z; v[3] = ep * x0.w + a0.w;
    v[4] = ep * x1.x + a1.x; v[5] = ep * x1.y + a1.y;
    v[6] = ep * x1.z + a1.z; v[7] = ep * x1.w + a1.w;
  } else {
#pragma unroll
    for (int e = 0; e < 8; ++e) v[e] = 0.0f;
  }
  unsigned short hh[8], ll[8];
#pragma unroll
  for (int e = 0; e < 8; ++e) {
    hh[e] = f2bf(v[e]);
    ll[e] = f2bf(v[e] - bf2f(hh[e]));
  }
  vh[p] = pack8(hh);
  vl[p] = pack8(ll);
}

// GEMM1 + BN + tanh + split + repack for GEMM2.
__launch_bounds__(256, 2)
__global__ void k_g1(const uint4* __restrict__ vh, const uint4* __restrict__ vl,
                     const uint4* __restrict__ w1h, const uint4* __restrict__ w1l,
                     const float* __restrict__ sc, const float* __restrict__ sh,
                     uint4* __restrict__ hh, uint4* __restrict__ hl, int NTiles) {
  __shared__ uint4 sBh[1024], sBl[1024];
  __shared__ float ssc[TWO_DIM], ssh[TWO_DIM];
  __shared__ float sH[4 * 16 * 132];

  int t = threadIdx.x;
#pragma unroll
  for (int q = 0; q < 4; ++q) {
    sBh[q * 256 + t] = w1h[q * 256 + t];
    sBl[q * 256 + t] = w1l[q * 256 + t];
  }
  if (t < TWO_DIM) {
    ssc[t] = sc[t];
    ssh[t] = sh[t];
  }
  __syncthreads();

  const int wid = t >> 6, lane = t & 63;
  const int T = blockIdx.x * 4 + wid;
  if (T >= NTiles) return;
  const int c = lane & 15, g = lane >> 4;

  const bf16x8* Ah = reinterpret_cast<const bf16x8*>(vh + (size_t)T * 128);
  const bf16x8* Al = reinterpret_cast<const bf16x8*>(vl + (size_t)T * 128);
  bf16x8 ah0 = Ah[lane], ah1 = Ah[64 + lane];
  bf16x8 al0 = Al[lane], al1 = Al[64 + lane];

  const bf16x8* Bh = reinterpret_cast<const bf16x8*>(sBh);
  const bf16x8* Bl = reinterpret_cast<const bf16x8*>(sBl);
  float* myH = sH + wid * (16 * 132);

#pragma unroll
  for (int nt = 0; nt < 8; ++nt) {
    f32x4 acc = {0.f, 0.f, 0.f, 0.f};
    bf16x8 bh0 = Bh[(nt * 2 + 0) * 64 + lane];
    bf16x8 bl0 = Bl[(nt * 2 + 0) * 64 + lane];
    bf16x8 bh1 = Bh[(nt * 2 + 1) * 64 + lane];
    bf16x8 bl1 = Bl[(nt * 2 + 1) * 64 + lane];
    acc = MFMA16(ah0, bh0, acc);
    acc = MFMA16(ah1, bh1, acc);
    acc = MFMA16(ah0, bl0, acc);
    acc = MFMA16(ah1, bl1, acc);
    acc = MFMA16(al0, bh0, acc);
    acc = MFMA16(al1, bh1, acc);
    int j = nt * 16 + c;
    float scj = ssc[j], shj = ssh[j];
#pragma unroll
    for (int r = 0; r < 4; ++r)
      myH[(g * 4 + r) * 132 + j] = fast_tanh(acc[r] * scj + shj);
  }

#pragma unroll
  for (int f2 = 0; f2 < 4; ++f2) {
    const float* hp = myH + c * 132 + f2 * 32 + g * 8;
    float4 v0 = *reinterpret_cast<const float4*>(hp);
    float4 v1 = *reinterpret_cast<const float4*>(hp + 4);
    float vv[8] = {v0.x, v0.y, v0.z, v0.w, v1.x, v1.y, v1.z, v1.w};
    unsigned short H[8], L[8];
#pragma unroll
    for (int e = 0; e < 8; ++e) {
      H[e] = f2bf(vv[e]);
      L[e] = f2bf(vv[e] - bf2f(H[e]));
    }
    size_t o = ((size_t)T * 4 + f2) * 64 + lane;
    hh[o] = pack8(H);
    hl[o] = pack8(L);
  }
}

// GEMM2 + tanh (+pool). C = H[16x128] @ W2[128x64].
template <bool POOL>
__launch_bounds__(256, 2)
__global__ void k_g2(const uint4* __restrict__ hh, const uint4* __restrict__ hl,
                     const uint4* __restrict__ w2h, const uint4* __restrict__ w2l,
                     const float* __restrict__ b2, float* __restrict__ hout,
                     float* __restrict__ pooled, const int* __restrict__ batch,
                     int n, int NTiles) {
  __shared__ uint4 sBh[1024], sBl[1024];
  __shared__ float sb2[DIM];

  int t = threadIdx.x;
#pragma unroll
  for (int q = 0; q < 4; ++q) {
    sBh[q * 256 + t] = w2h[q * 256 + t];
    sBl[q * 256 + t] = w2l[q * 256 + t];
  }
  if (t < DIM) sb2[t] = b2[t];
  __syncthreads();

  const int wid = t >> 6, lane = t & 63;
  const int T = blockIdx.x * 4 + wid;
  if (T >= NTiles) return;
  const int c = lane & 15, g = lane >> 4;

  const bf16x8* Ah = reinterpret_cast<const bf16x8*>(hh + (size_t)T * 256);
  const bf16x8* Al = reinterpret_cast<const bf16x8*>(hl + (size_t)T * 256);
  bf16x8 ah0 = Ah[lane], ah1 = Ah[64 + lane], ah2 = Ah[128 + lane], ah3 = Ah[192 + lane];
  bf16x8 al0 = Al[lane], al1 = Al[64 + lane], al2 = Al[128 + lane], al3 = Al[192 + lane];

  const bf16x8* Bh = reinterpret_cast<const bf16x8*>(sBh);
  const bf16x8* Bl = reinterpret_cast<const bf16x8*>(sBl);

  bool uni = false;
  int b0 = 0;
  if (POOL) {
    b0 = batch[min(T * 16, n - 1)];
    int b15 = batch[min(T * 16 + 15, n - 1)];
    uni = (b0 == b15) && (T * 16 + 15 < n);
  }

#pragma unroll
  for (int nt = 0; nt < 4; ++nt) {
    f32x4 acc = {0.f, 0.f, 0.f, 0.f};
    bf16x8 bh0 = Bh[(nt * 4 + 0) * 64 + lane];
    bf16x8 bh1 = Bh[(nt * 4 + 1) * 64 + lane];
    bf16x8 bh2 = Bh[(nt * 4 + 2) * 64 + lane];
    bf16x8 bh3 = Bh[(nt * 4 + 3) * 64 + lane];
    bf16x8 bl0 = Bl[(nt * 4 + 0) * 64 + lane];
    bf16x8 bl1 = Bl[(nt * 4 + 1) * 64 + lane];
    bf16x8 bl2 = Bl[(nt * 4 + 2) * 64 + lane];
    bf16x8 bl3 = Bl[(nt * 4 + 3) * 64 + lane];
    acc = MFMA16(ah0, bh0, acc);
    acc = MFMA16(ah1, bh1, acc);
    acc = MFMA16(ah2, bh2, acc);
    acc = MFMA16(ah3, bh3, acc);
    acc = MFMA16(ah0, bl0, acc);
    acc = MFMA16(ah1, bl1, acc);
    acc = MFMA16(ah2, bl2, acc);
    acc = MFMA16(ah3, bl3, acc);
    acc = MFMA16(al0, bh0, acc);
    acc = MFMA16(al1, bh1, acc);
    acc = MFMA16(al2, bh2, acc);
    acc = MFMA16(al3, bh3, acc);

    int j = nt * 16 + c;
    float bj = sb2[j];
    float o0 = fast_tanh(acc[0] + bj);
    float o1 = fast_tanh(acc[1] + bj);
    float o2 = fast_tanh(acc[2] + bj);
    float o3 = fast_tanh(acc[3] + bj);
    if (POOL) {
      if (uni) {
        float os = (o0 + o1) + (o2 + o3);
        os += __shfl_xor(os, 16);
        os += __shfl_xor(os, 32);
        if (g == 0) atomicAdd(&pooled[(size_t)b0 * DIM + j], os);
      } else {
        int mb = T * 16 + g * 4;
#pragma unroll
        for (int r = 0; r < 4; ++r) {
          int m = mb + r;
          float o = (r == 0) ? o0 : (r == 1) ? o1 : (r == 2) ? o2 : o3;
          if (m < n) atomicAdd(&pooled[(size_t)batch[m] * DIM + j], o);
        }
      }
    } else {
      int mb = T * 16 + g * 4;
      if (mb + 0 < n) hout[(size_t)(mb + 0) * DIM + j] = o0;
      if (mb + 1 < n) hout[(size_t)(mb + 1) * DIM + j] = o1;
      if (mb + 2 < n) hout[(size_t)(mb + 2) * DIM + j] = o2;
      if (mb + 3 < n) hout[(size_t)(mb + 3) * DIM + j] = o3;
    }
  }
}

// out[g][i] = tanh( (pooled[g]/max(cnt,1)) . linW[:,i] + linb[i] )
__global__ void k_out(const float* __restrict__ pooled, const int* __restrict__ cnt,
                      const float* __restrict__ linW, const float* __restrict__ linb,
                      float* __restrict__ out) {
  int g = blockIdx.x;
  int i = threadIdx.x;
  int c = cnt[g];
  float inv = 1.0f / (float)(c > 0 ? c : 1);
  float acc = 0.0f;
#pragma unroll
  for (int k = 0; k < DIM; ++k)
    acc += pooled[(size_t)g * DIM + k] * linW[k * DIM + i];
  out[(size_t)g * DIM + i] = fast_tanh(acc * inv + linb[i]);
}

extern "C" void kernel_launch(void* const* d_in, const int* in_sizes, int n_in,
                              void* d_out, int out_size, void* d_ws, size_t ws_size,
                              hipStream_t stream) {
  const float* x = (const float*)d_in[0];
  const int* ei = (const int*)d_in[1];
  const int* batch = (const int*)d_in[2];
  const float* eps1 = (const float*)d_in[3];
  const float* W11 = (const float*)d_in[4];
  const float* b11 = (const float*)d_in[5];
  const float* g1 = (const float*)d_in[6];
  const float* be1 = (const float*)d_in[7];
  const float* W12 = (const float*)d_in[8];
  const float* b12 = (const float*)d_in[9];
  const float* eps2 = (const float*)d_in[10];
  const float* W21 = (const float*)d_in[11];
  const float* b21 = (const float*)d_in[12];
  const float* g2 = (const float*)d_in[13];
  const float* be2 = (const float*)d_in[14];
  const float* W22 = (const float*)d_in[15];
  const float* b22 = (const float*)d_in[16];
  const float* linW = (const float*)d_in[17];
  const float* linb = (const float*)d_in[18];

  const int n = in_sizes[0] / DIM;  // 100000
  const int E = in_sizes[1] / 2;    // 1600000
  const int G = out_size / DIM;     // 256
  const int* src = ei;
  const int* dst = ei + E;
  const int NT = (n + 15) / 16;     // 6250
  const int P = NT * 128;

  size_t off = 0;
  auto alloc = [&](size_t bytes) -> void* {
    void* p = (char*)d_ws + off;
    off += (bytes + 255) & ~(size_t)255;
    return p;
  };
  float* agg = (float*)alloc((size_t)n * DIM * 4);
  float* h1 = (float*)alloc((size_t)n * DIM * 4);
  uint4* vhi = (uint4*)alloc((size_t)P * 16);
  uint4* vlo = (uint4*)alloc((size_t)P * 16);
  uint4* hhi = (uint4*)alloc((size_t)NT * 256 * 16);
  uint4* hlo = (uint4*)alloc((size_t)NT * 256 * 16);
  int* deg = (int*)alloc((size_t)n * 4);
  int* offs = (int*)alloc((size_t)n * 4);
  int* cursor = (int*)alloc((size_t)n * 4);
  int* csr = (int*)alloc((size_t)E * 4);
  float* sc1 = (float*)alloc(TWO_DIM * 4);
  float* sh1 = (float*)alloc(TWO_DIM * 4);
  float* sc2 = (float*)alloc(TWO_DIM * 4);
  float* sh2 = (float*)alloc(TWO_DIM * 4);
  uint4* w1hA = (uint4*)alloc(1024 * 16);
  uint4* w1lA = (uint4*)alloc(1024 * 16);
  uint4* w2hA = (uint4*)alloc(1024 * 16);
  uint4* w2lA = (uint4*)alloc(1024 * 16);
  uint4* w1hB = (uint4*)alloc(1024 * 16);
  uint4* w1lB = (uint4*)alloc(1024 * 16);
  uint4* w2hB = (uint4*)alloc(1024 * 16);
  uint4* w2lB = (uint4*)alloc(1024 * 16);
  float* pooled = (float*)alloc((size_t)G * DIM * 4);
  int* cnt = (int*)alloc((size_t)G * 4);
  int* bsum = (int*)alloc(512 * 4);

  hipMemsetAsync(deg, 0, (size_t)n * 4, stream);
  hipMemsetAsync(cnt, 0, (size_t)G * 4, stream);
  hipMemsetAsync(pooled, 0, (size_t)G * DIM * 4, stream);

  const int nb = (n + 255) / 256;
  k_hist_dst<<<1024, 256, 0, stream>>>(dst, deg, E, n);
  k_hist256<<<64, 256, 0, stream>>>(batch, cnt, n);
  k_scan_part<<<nb, 256, 0, stream>>>(deg, bsum, n);
  k_scan_mid<<<1, 512, 0, stream>>>(bsum, nb);
  k_scan_final<<<nb, 256, 0, stream>>>(deg, bsum, offs, cursor, n);
  k_scatter<<<1024, 256, 0, stream>>>(src, dst, cursor, csr, E, n);
  k_prep<<<1, TWO_DIM, 0, stream>>>(b11, g1, be1, sc1, sh1);
  k_prep<<<1, TWO_DIM, 0, stream>>>(b21, g2, be2, sc2, sh2);
  k_prepw<<<8, 256, 0, stream>>>(W11, W12, w1hA, w1lA, w2hA, w2lA);
  k_prepw<<<8, 256, 0, stream>>>(W21, W22, w1hB, w1lB, w2hB, w2lB);

  const int gT = (NT + 3) / 4;
  // GIN layer 1
  k_gather<<<(n + 3) / 4, 256, 0, stream>>>(x, csr, offs, deg, agg, n);
  k_split<<<(P + 255) / 256, 256, 0, stream>>>(x, agg, eps1, vhi, vlo, n, P);
  k_g1<<<gT, 256, 0, stream>>>(vhi, vlo, w1hA, w1lA, sc1, sh1, hhi, hlo, NT);
  k_g2<false><<<gT, 256, 0, stream>>>(hhi, hlo, w2hA, w2lA, b12, h1, nullptr,
                                      nullptr, n, NT);
  // GIN layer 2
  k_gather<<<(n + 3) / 4, 256, 0, stream>>>(h1, csr, offs, deg, agg, n);
  k_split<<<(P + 255) / 256, 256, 0, stream>>>(h1, agg, eps2, vhi, vlo, n, P);
  k_g1<<<gT, 256, 0, stream>>>(vhi, vlo, w1hB, w1lB, sc2, sh2, hhi, hlo, NT);
  k_g2<true><<<gT, 256, 0, stream>>>(hhi, hlo, w2hB, w2lB, b22, nullptr, pooled,
                                     batch, n, NT);
  k_out<<<G, DIM, 0, stream>>>(pooled, cnt, linW, linb, (float*)d_out);
}

// Round 11
// 372.939 us; speedup vs baseline: 3.5008x; 1.0462x over previous
//
#include <hip/hip_runtime.h>

#define DIM 64
#define TWO_DIM 128

typedef __attribute__((ext_vector_type(8))) short bf16x8;
typedef __attribute__((ext_vector_type(4))) float f32x4;
#define MFMA16(A, B, C) __builtin_amdgcn_mfma_f32_16x16x32_bf16(A, B, C, 0, 0, 0)

__device__ __forceinline__ float fast_tanh(float x) {
  float cx = fminf(fmaxf(x, -15.0f), 15.0f);
  float e = __expf(2.0f * cx);
  return (e - 1.0f) / (e + 1.0f);
}

__device__ __forceinline__ unsigned short f2bf(float x) {
  unsigned int b = __float_as_uint(x);
  unsigned int r = b + 0x7FFFu + ((b >> 16) & 1u);
  return (unsigned short)(r >> 16);
}
__device__ __forceinline__ float bf2f(unsigned short h) {
  return __uint_as_float(((unsigned int)h) << 16);
}
__device__ __forceinline__ uint4 pack8(const unsigned short* s) {
  uint4 u;
  u.x = (unsigned)s[0] | ((unsigned)s[1] << 16);
  u.y = (unsigned)s[2] | ((unsigned)s[3] << 16);
  u.z = (unsigned)s[4] | ((unsigned)s[5] << 16);
  u.w = (unsigned)s[6] | ((unsigned)s[7] << 16);
  return u;
}

// ---------------- graph machinery ----------------
__global__ void k_hist_dst(const int* __restrict__ dst, int* __restrict__ cnt,
                           int E, int n) {
  const int r = blockIdx.x & 7;
  const int sub = blockIdx.x >> 3;
  const int nsub = gridDim.x >> 3;
  const int span = (n + 7) >> 3;
  const int lo = r * span;
  const int hi = min(n, lo + span);

  int tid = sub * blockDim.x + threadIdx.x;
  int stride = nsub * blockDim.x;
  int E4 = E >> 2;
  const int4* p = reinterpret_cast<const int4*>(dst);
  for (int i = tid; i < E4; i += stride) {
    int4 v = p[i];
    if (v.x >= lo && v.x < hi) atomicAdd(&cnt[v.x], 1);
    if (v.y >= lo && v.y < hi) atomicAdd(&cnt[v.y], 1);
    if (v.z >= lo && v.z < hi) atomicAdd(&cnt[v.z], 1);
    if (v.w >= lo && v.w < hi) atomicAdd(&cnt[v.w], 1);
  }
  if (blockIdx.x == 0 && threadIdx.x == 0) {
    for (int i = E4 << 2; i < E; ++i) atomicAdd(&cnt[dst[i]], 1);
  }
}

__global__ void k_hist256(const int* __restrict__ idx, int* __restrict__ cnt,
                          int n) {
  __shared__ int h[256];
  int t = threadIdx.x;
  h[t] = 0;
  __syncthreads();
  int tid = blockIdx.x * blockDim.x + t;
  int stride = gridDim.x * blockDim.x;
  int n4 = n >> 2;
  const int4* p = reinterpret_cast<const int4*>(idx);
  for (int i = tid; i < n4; i += stride) {
    int4 v = p[i];
    atomicAdd(&h[v.x & 255], 1);
    atomicAdd(&h[v.y & 255], 1);
    atomicAdd(&h[v.z & 255], 1);
    atomicAdd(&h[v.w & 255], 1);
  }
  if (tid == 0) {
    for (int i = n4 << 2; i < n; ++i) atomicAdd(&cnt[idx[i]], 1);
  }
  __syncthreads();
  if (h[t] > 0) atomicAdd(&cnt[t], h[t]);
}

__global__ void k_scan_part(const int* __restrict__ deg, int* __restrict__ bsum,
                            int n) {
  __shared__ int red[256];
  int t = threadIdx.x;
  int i = blockIdx.x * 256 + t;
  red[t] = (i < n) ? deg[i] : 0;
  __syncthreads();
#pragma unroll
  for (int off = 128; off >= 1; off >>= 1) {
    if (t < off) red[t] += red[t + off];
    __syncthreads();
  }
  if (t == 0) bsum[blockIdx.x] = red[0];
}

__global__ void k_scan_mid(int* __restrict__ bsum, int nb) {
  __shared__ int s[512];
  int t = threadIdx.x;
  int v = (t < nb) ? bsum[t] : 0;
  s[t] = v;
  __syncthreads();
#pragma unroll
  for (int off = 1; off < 512; off <<= 1) {
    int u = (t >= off) ? s[t - off] : 0;
    __syncthreads();
    s[t] += u;
    __syncthreads();
  }
  if (t < nb) bsum[t] = s[t] - v;
}

__global__ void k_scan_final(const int* __restrict__ deg, const int* __restrict__ bsum,
                             int* __restrict__ offs, int* __restrict__ cursor, int n) {
  __shared__ int s[256];
  int t = threadIdx.x;
  int i = blockIdx.x * 256 + t;
  int d = (i < n) ? deg[i] : 0;
  s[t] = d;
  __syncthreads();
#pragma unroll
  for (int off = 1; off < 256; off <<= 1) {
    int u = (t >= off) ? s[t - off] : 0;
    __syncthreads();
    s[t] += u;
    __syncthreads();
  }
  int ex = bsum[blockIdx.x] + s[t] - d;
  if (i < n) {
    offs[i] = ex;
    cursor[i] = ex;
  }
}

__global__ void k_scatter(const int* __restrict__ src, const int* __restrict__ dst,
                          int* __restrict__ cursor, int* __restrict__ csr, int E,
                          int n) {
  const int r = blockIdx.x & 7;
  const int sub = blockIdx.x >> 3;
  const int nsub = gridDim.x >> 3;
  const int span = (n + 7) >> 3;
  const int lo = r * span;
  const int hi = min(n, lo + span);

  int tid = sub * blockDim.x + threadIdx.x;
  int stride = nsub * blockDim.x;
  int E4 = E >> 2;
  const int4* s4 = reinterpret_cast<const int4*>(src);
  const int4* d4 = reinterpret_cast<const int4*>(dst);
  for (int i = tid; i < E4; i += stride) {
    int4 d = d4[i];
    bool a0 = (d.x >= lo) & (d.x < hi);
    bool a1 = (d.y >= lo) & (d.y < hi);
    bool a2 = (d.z >= lo) & (d.z < hi);
    bool a3 = (d.w >= lo) & (d.w < hi);
    if (a0 | a1 | a2 | a3) {
      int4 s = s4[i];
      if (a0) { int p = atomicAdd(&cursor[d.x], 1); csr[p] = s.x; }
      if (a1) { int p = atomicAdd(&cursor[d.y], 1); csr[p] = s.y; }
      if (a2) { int p = atomicAdd(&cursor[d.z], 1); csr[p] = s.z; }
      if (a3) { int p = atomicAdd(&cursor[d.w], 1); csr[p] = s.w; }
    }
  }
  if (blockIdx.x == 0 && threadIdx.x == 0) {
    for (int i = E4 << 2; i < E; ++i) {
      int p = atomicAdd(&cursor[dst[i]], 1);
      csr[p] = src[i];
    }
  }
}

// one 64-lane wave per node; lane = feature; 8-wide MLP-unrolled edge loop
__global__ void k_gather(const float* __restrict__ x, const int* __restrict__ csr,
                         const int* __restrict__ offs, const int* __restrict__ deg,
                         float* __restrict__ agg, int n) {
  int node = blockIdx.x * 4 + (threadIdx.x >> 6);
  int t = threadIdx.x & 63;
  if (node >= n) return;
  int s = offs[node], d = deg[node];
  float a0 = 0.f, a1 = 0.f, a2 = 0.f, a3 = 0.f;
  float a4 = 0.f, a5 = 0.f, a6 = 0.f, a7 = 0.f;
  for (int base = 0; base < d; base += 64) {
    int m = min(64, d - base);
    int myi = (t < m) ? csr[s + base + t] : 0;
    int i = 0;
    for (; i + 8 <= m; i += 8) {
      int s0 = __shfl(myi, i + 0);
      int s1 = __shfl(myi, i + 1);
      int s2 = __shfl(myi, i + 2);
      int s3 = __shfl(myi, i + 3);
      int s4 = __shfl(myi, i + 4);
      int s5 = __shfl(myi, i + 5);
      int s6 = __shfl(myi, i + 6);
      int s7 = __shfl(myi, i + 7);
      float v0 = x[(size_t)s0 * DIM + t];
      float v1 = x[(size_t)s1 * DIM + t];
      float v2 = x[(size_t)s2 * DIM + t];
      float v3 = x[(size_t)s3 * DIM + t];
      float v4 = x[(size_t)s4 * DIM + t];
      float v5 = x[(size_t)s5 * DIM + t];
      float v6 = x[(size_t)s6 * DIM + t];
      float v7 = x[(size_t)s7 * DIM + t];
      a0 += v0; a1 += v1; a2 += v2; a3 += v3;
      a4 += v4; a5 += v5; a6 += v6; a7 += v7;
    }
    if (i + 4 <= m) {
      int s0 = __shfl(myi, i + 0);
      int s1 = __shfl(myi, i + 1);
      int s2 = __shfl(myi, i + 2);
      int s3 = __shfl(myi, i + 3);
      float v0 = x[(size_t)s0 * DIM + t];
      float v1 = x[(size_t)s1 * DIM + t];
      float v2 = x[(size_t)s2 * DIM + t];
      float v3 = x[(size_t)s3 * DIM + t];
      a0 += v0; a1 += v1; a2 += v2; a3 += v3;
      i += 4;
    }
    for (; i < m; ++i) {
      int sn = __shfl(myi, i);
      a0 += x[(size_t)sn * DIM + t];
    }
  }
  agg[(size_t)node * DIM + t] = ((a0 + a1) + (a2 + a3)) + ((a4 + a5) + (a6 + a7));
}

// fold BN(eval) into scale/shift
__global__ void k_prep(const float* __restrict__ b1, const float* __restrict__ gamma,
                       const float* __restrict__ beta, float* __restrict__ sc,
                       float* __restrict__ sh) {
  int i = threadIdx.x;
  if (i < TWO_DIM) {
    float s = gamma[i] * rsqrtf(1.0f + 1e-5f);
    sc[i] = s;
    sh[i] = b1[i] * s + beta[i];
  }
}

// Pack W1 [64][128] and W2 [128][64] into MFMA B-fragment order, hi/lo bf16 split.
__global__ void k_prepw(const float* __restrict__ W1, const float* __restrict__ W2,
                        uint4* __restrict__ w1h, uint4* __restrict__ w1l,
                        uint4* __restrict__ w2h, uint4* __restrict__ w2l) {
  int p = blockIdx.x * 256 + threadIdx.x;  // 0..2047
  if (p >= 2048) return;
  int lane = p & 63;
  int c = lane & 15, g = lane >> 4;
  unsigned short hh[8], ll[8];
  if (p < 1024) {
    int nt = p >> 7, f = (p >> 6) & 1;
    int nn = nt * 16 + c, kb = f * 32 + g * 8;
#pragma unroll
    for (int e = 0; e < 8; ++e) {
      float w = W1[(kb + e) * TWO_DIM + nn];
      hh[e] = f2bf(w);
      ll[e] = f2bf(w - bf2f(hh[e]));
    }
    w1h[p] = pack8(hh);
    w1l[p] = pack8(ll);
  } else {
    int q = p - 1024;
    int nt = q >> 8, f = (q >> 6) & 3;
    int nn = nt * 16 + c, kb = f * 32 + g * 8;
#pragma unroll
    for (int e = 0; e < 8; ++e) {
      float w = W2[(kb + e) * DIM + nn];
      hh[e] = f2bf(w);
      ll[e] = f2bf(w - bf2f(hh[e]));
    }
    w2h[q] = pack8(hh);
    w2l[q] = pack8(ll);
  }
}

// v = (1+eps)*x + agg, split hi/lo bf16, packed in MFMA A-frag order.
__global__ void k_split(const float* __restrict__ xin, const float* __restrict__ agg,
                        const float* __restrict__ epsp, uint4* __restrict__ vh,
                        uint4* __restrict__ vl, int n, int P) {
  int p = blockIdx.x * 256 + threadIdx.x;
  if (p >= P) return;
  float ep = 1.0f + epsp[0];
  int lane = p & 63;
  int T = p >> 7;
  int f = (p >> 6) & 1;
  int m = T * 16 + (lane & 15);
  int k0 = f * 32 + (lane >> 4) * 8;
  float v[8];
  if (m < n) {
    const float4* xa = reinterpret_cast<const float4*>(xin + (size_t)m * DIM + k0);
    const float4* aa = reinterpret_cast<const float4*>(agg + (size_t)m * DIM + k0);
    float4 x0 = xa[0], x1 = xa[1], a0 = aa[0], a1 = aa[1];
    v[0] = ep * x0.x + a0.x; v[1] = ep * x0.y + a0.y;
    v[2] = ep * x0.z + a0.z; v[3] = ep * x0.w + a0.w;
    v[4] = ep * x1.x + a1.x; v[5] = ep * x1.y + a1.y;
    v[6] = ep * x1.z + a1.z; v[7] = ep * x1.w + a1.w;
  } else {
#pragma unroll
    for (int e = 0; e < 8; ++e) v[e] = 0.0f;
  }
  unsigned short hh[8], ll[8];
#pragma unroll
  for (int e = 0; e < 8; ++e) {
    hh[e] = f2bf(v[e]);
    ll[e] = f2bf(v[e] - bf2f(hh[e]));
  }
  vh[p] = pack8(hh);
  vl[p] = pack8(ll);
}

// Fused GIN MLP: GEMM1 + BN + tanh + in-register repack + GEMM2 + tanh (+pool).
// One wave = one 16-node tile; H tile never leaves the CU (per-wave LDS chunk
// for the lane-transpose, 16x36 floats per wave).
template <bool POOL>
__launch_bounds__(256, 2)
__global__ void k_fused(const uint4* __restrict__ vh, const uint4* __restrict__ vl,
                        const uint4* __restrict__ w1h, const uint4* __restrict__ w1l,
                        const uint4* __restrict__ w2h, const uint4* __restrict__ w2l,
                        const float* __restrict__ sc, const float* __restrict__ sh,
                        const float* __restrict__ b2, float* __restrict__ hout,
                        float* __restrict__ pooled, const int* __restrict__ batch,
                        int n, int NTiles) {
  __shared__ uint4 sB1h[1024], sB1l[1024];  // W1 frags, 32 KB
  __shared__ uint4 sB2h[1024], sB2l[1024];  // W2 frags, 32 KB
  __shared__ float ssc[TWO_DIM], ssh[TWO_DIM], sb2[DIM];
  __shared__ float sHc[4][16 * 36];         // per-wave H chunk, 9.2 KB

  int t = threadIdx.x;
#pragma unroll
  for (int q = 0; q < 4; ++q) {
    sB1h[q * 256 + t] = w1h[q * 256 + t];
    sB1l[q * 256 + t] = w1l[q * 256 + t];
    sB2h[q * 256 + t] = w2h[q * 256 + t];
    sB2l[q * 256 + t] = w2l[q * 256 + t];
  }
  if (t < TWO_DIM) {
    ssc[t] = sc[t];
    ssh[t] = sh[t];
  }
  if (t < DIM) sb2[t] = b2[t];
  __syncthreads();

  const int wid = t >> 6, lane = t & 63;
  const int T = blockIdx.x * 4 + wid;
  if (T >= NTiles) return;
  const int c = lane & 15, g = lane >> 4;

  // V A-frags (packed by k_split)
  const bf16x8* Ah = reinterpret_cast<const bf16x8*>(vh + (size_t)T * 128);
  const bf16x8* Al = reinterpret_cast<const bf16x8*>(vl + (size_t)T * 128);
  bf16x8 vah0 = Ah[lane], vah1 = Ah[64 + lane];
  bf16x8 val0 = Al[lane], val1 = Al[64 + lane];

  const bf16x8* B1h = reinterpret_cast<const bf16x8*>(sB1h);
  const bf16x8* B1l = reinterpret_cast<const bf16x8*>(sB1l);
  const bf16x8* B2h = reinterpret_cast<const bf16x8*>(sB2h);
  const bf16x8* B2l = reinterpret_cast<const bf16x8*>(sB2l);
  float* myH = &sHc[wid][0];

  // ---- GEMM1 + BN + tanh, chunked by 32 hidden columns; repack to A-frags
  bf16x8 hhf[4], hlf[4];
#pragma unroll
  for (int f2 = 0; f2 < 4; ++f2) {
#pragma unroll
    for (int q = 0; q < 2; ++q) {
      int nt = 2 * f2 + q;
      f32x4 acc = {0.f, 0.f, 0.f, 0.f};
      bf16x8 bh0 = B1h[(nt * 2 + 0) * 64 + lane];
      bf16x8 bl0 = B1l[(nt * 2 + 0) * 64 + lane];
      bf16x8 bh1 = B1h[(nt * 2 + 1) * 64 + lane];
      bf16x8 bl1 = B1l[(nt * 2 + 1) * 64 + lane];
      acc = MFMA16(vah0, bh0, acc);
      acc = MFMA16(vah1, bh1, acc);
      acc = MFMA16(vah0, bl0, acc);
      acc = MFMA16(vah1, bl1, acc);
      acc = MFMA16(val0, bh0, acc);
      acc = MFMA16(val1, bh1, acc);
      int j = nt * 16 + c;
      float scj = ssc[j], shj = ssh[j];
#pragma unroll
      for (int r = 0; r < 4; ++r)
        myH[(g * 4 + r) * 36 + q * 16 + c] = fast_tanh(acc[r] * scj + shj);
    }
    // wave-local lane-transpose read (compiler orders via lgkmcnt)
    const float* hp = myH + c * 36 + g * 8;
    float4 v0 = *reinterpret_cast<const float4*>(hp);
    float4 v1 = *reinterpret_cast<const float4*>(hp + 4);
    float vv[8] = {v0.x, v0.y, v0.z, v0.w, v1.x, v1.y, v1.z, v1.w};
    unsigned short H8[8], L8[8];
#pragma unroll
    for (int e = 0; e < 8; ++e) {
      H8[e] = f2bf(vv[e]);
      L8[e] = f2bf(vv[e] - bf2f(H8[e]));
    }
    uint4 uh = pack8(H8), ul = pack8(L8);
    hhf[f2] = *reinterpret_cast<bf16x8*>(&uh);
    hlf[f2] = *reinterpret_cast<bf16x8*>(&ul);
  }

  // ---- GEMM2 + bias + tanh (+pool)
  bool uni = false;
  int b0 = 0;
  if (POOL) {
    b0 = batch[min(T * 16, n - 1)];
    int b15 = batch[min(T * 16 + 15, n - 1)];
    uni = (b0 == b15) && (T * 16 + 15 < n);
  }

#pragma unroll
  for (int nt = 0; nt < 4; ++nt) {
    f32x4 acc = {0.f, 0.f, 0.f, 0.f};
    bf16x8 bh0 = B2h[(nt * 4 + 0) * 64 + lane];
    bf16x8 bh1 = B2h[(nt * 4 + 1) * 64 + lane];
    bf16x8 bh2 = B2h[(nt * 4 + 2) * 64 + lane];
    bf16x8 bh3 = B2h[(nt * 4 + 3) * 64 + lane];
    bf16x8 bl0 = B2l[(nt * 4 + 0) * 64 + lane];
    bf16x8 bl1 = B2l[(nt * 4 + 1) * 64 + lane];
    bf16x8 bl2 = B2l[(nt * 4 + 2) * 64 + lane];
    bf16x8 bl3 = B2l[(nt * 4 + 3) * 64 + lane];
    acc = MFMA16(hhf[0], bh0, acc);
    acc = MFMA16(hhf[1], bh1, acc);
    acc = MFMA16(hhf[2], bh2, acc);
    acc = MFMA16(hhf[3], bh3, acc);
    acc = MFMA16(hhf[0], bl0, acc);
    acc = MFMA16(hhf[1], bl1, acc);
    acc = MFMA16(hhf[2], bl2, acc);
    acc = MFMA16(hhf[3], bl3, acc);
    acc = MFMA16(hlf[0], bh0, acc);
    acc = MFMA16(hlf[1], bh1, acc);
    acc = MFMA16(hlf[2], bh2, acc);
    acc = MFMA16(hlf[3], bh3, acc);

    int j = nt * 16 + c;
    float bj = sb2[j];
    float o0 = fast_tanh(acc[0] + bj);
    float o1 = fast_tanh(acc[1] + bj);
    float o2 = fast_tanh(acc[2] + bj);
    float o3 = fast_tanh(acc[3] + bj);
    if (POOL) {
      if (uni) {
        float os = (o0 + o1) + (o2 + o3);
        os += __shfl_xor(os, 16);
        os += __shfl_xor(os, 32);
        if (g == 0) atomicAdd(&pooled[(size_t)b0 * DIM + j], os);
      } else {
        int mb = T * 16 + g * 4;
#pragma unroll
        for (int r = 0; r < 4; ++r) {
          int m = mb + r;
          float o = (r == 0) ? o0 : (r == 1) ? o1 : (r == 2) ? o2 : o3;
          if (m < n) atomicAdd(&pooled[(size_t)batch[m] * DIM + j], o);
        }
      }
    } else {
      int mb = T * 16 + g * 4;
      if (mb + 0 < n) hout[(size_t)(mb + 0) * DIM + j] = o0;
      if (mb + 1 < n) hout[(size_t)(mb + 1) * DIM + j] = o1;
      if (mb + 2 < n) hout[(size_t)(mb + 2) * DIM + j] = o2;
      if (mb + 3 < n) hout[(size_t)(mb + 3) * DIM + j] = o3;
    }
  }
}

// out[g][i] = tanh( (pooled[g]/max(cnt,1)) . linW[:,i] + linb[i] )
__global__ void k_out(const float* __restrict__ pooled, const int* __restrict__ cnt,
                      const float* __restrict__ linW, const float* __restrict__ linb,
                      float* __restrict__ out) {
  int g = blockIdx.x;
  int i = threadIdx.x;
  int c = cnt[g];
  float inv = 1.0f / (float)(c > 0 ? c : 1);
  float acc = 0.0f;
#pragma unroll
  for (int k = 0; k < DIM; ++k)
    acc += pooled[(size_t)g * DIM + k] * linW[k * DIM + i];
  out[(size_t)g * DIM + i] = fast_tanh(acc * inv + linb[i]);
}

extern "C" void kernel_launch(void* const* d_in, const int* in_sizes, int n_in,
                              void* d_out, int out_size, void* d_ws, size_t ws_size,
                              hipStream_t stream) {
  const float* x = (const float*)d_in[0];
  const int* ei = (const int*)d_in[1];
  const int* batch = (const int*)d_in[2];
  const float* eps1 = (const float*)d_in[3];
  const float* W11 = (const float*)d_in[4];
  const float* b11 = (const float*)d_in[5];
  const float* g1 = (const float*)d_in[6];
  const float* be1 = (const float*)d_in[7];
  const float* W12 = (const float*)d_in[8];
  const float* b12 = (const float*)d_in[9];
  const float* eps2 = (const float*)d_in[10];
  const float* W21 = (const float*)d_in[11];
  const float* b21 = (const float*)d_in[12];
  const float* g2 = (const float*)d_in[13];
  const float* be2 = (const float*)d_in[14];
  const float* W22 = (const float*)d_in[15];
  const float* b22 = (const float*)d_in[16];
  const float* linW = (const float*)d_in[17];
  const float* linb = (const float*)d_in[18];

  const int n = in_sizes[0] / DIM;  // 100000
  const int E = in_sizes[1] / 2;    // 1600000
  const int G = out_size / DIM;     // 256
  const int* src = ei;
  const int* dst = ei + E;
  const int NT = (n + 15) / 16;     // 6250
  const int P = NT * 128;

  size_t off = 0;
  auto alloc = [&](size_t bytes) -> void* {
    void* p = (char*)d_ws + off;
    off += (bytes + 255) & ~(size_t)255;
    return p;
  };
  float* agg = (float*)alloc((size_t)n * DIM * 4);
  float* h1 = (float*)alloc((size_t)n * DIM * 4);
  uint4* vhi = (uint4*)alloc((size_t)P * 16);
  uint4* vlo = (uint4*)alloc((size_t)P * 16);
  int* deg = (int*)alloc((size_t)n * 4);
  int* offs = (int*)alloc((size_t)n * 4);
  int* cursor = (int*)alloc((size_t)n * 4);
  int* csr = (int*)alloc((size_t)E * 4);
  float* sc1 = (float*)alloc(TWO_DIM * 4);
  float* sh1 = (float*)alloc(TWO_DIM * 4);
  float* sc2 = (float*)alloc(TWO_DIM * 4);
  float* sh2 = (float*)alloc(TWO_DIM * 4);
  uint4* w1hA = (uint4*)alloc(1024 * 16);
  uint4* w1lA = (uint4*)alloc(1024 * 16);
  uint4* w2hA = (uint4*)alloc(1024 * 16);
  uint4* w2lA = (uint4*)alloc(1024 * 16);
  uint4* w1hB = (uint4*)alloc(1024 * 16);
  uint4* w1lB = (uint4*)alloc(1024 * 16);
  uint4* w2hB = (uint4*)alloc(1024 * 16);
  uint4* w2lB = (uint4*)alloc(1024 * 16);
  float* pooled = (float*)alloc((size_t)G * DIM * 4);
  int* cnt = (int*)alloc((size_t)G * 4);
  int* bsum = (int*)alloc(512 * 4);

  hipMemsetAsync(deg, 0, (size_t)n * 4, stream);
  hipMemsetAsync(cnt, 0, (size_t)G * 4, stream);
  hipMemsetAsync(pooled, 0, (size_t)G * DIM * 4, stream);

  const int nb = (n + 255) / 256;
  k_hist_dst<<<1024, 256, 0, stream>>>(dst, deg, E, n);
  k_hist256<<<64, 256, 0, stream>>>(batch, cnt, n);
  k_scan_part<<<nb, 256, 0, stream>>>(deg, bsum, n);
  k_scan_mid<<<1, 512, 0, stream>>>(bsum, nb);
  k_scan_final<<<nb, 256, 0, stream>>>(deg, bsum, offs, cursor, n);
  k_scatter<<<1024, 256, 0, stream>>>(src, dst, cursor, csr, E, n);
  k_prep<<<1, TWO_DIM, 0, stream>>>(b11, g1, be1, sc1, sh1);
  k_prep<<<1, TWO_DIM, 0, stream>>>(b21, g2, be2, sc2, sh2);
  k_prepw<<<8, 256, 0, stream>>>(W11, W12, w1hA, w1lA, w2hA, w2lA);
  k_prepw<<<8, 256, 0, stream>>>(W21, W22, w1hB, w1lB, w2hB, w2lB);

  const int gT = (NT + 3) / 4;
  // GIN layer 1
  k_gather<<<(n + 3) / 4, 256, 0, stream>>>(x, csr, offs, deg, agg, n);
  k_split<<<(P + 255) / 256, 256, 0, stream>>>(x, agg, eps1, vhi, vlo, n, P);
  k_fused<false><<<gT, 256, 0, stream>>>(vhi, vlo, w1hA, w1lA, w2hA, w2lA, sc1, sh1,
                                         b12, h1, nullptr, nullptr, n, NT);
  // GIN layer 2
  k_gather<<<(n + 3) / 4, 256, 0, stream>>>(h1, csr, offs, deg, agg, n);
  k_split<<<(P + 255) / 256, 256, 0, stream>>>(h1, agg, eps2, vhi, vlo, n, P);
  k_fused<true><<<gT, 256, 0, stream>>>(vhi, vlo, w1hB, w1lB, w2hB, w2lB, sc2, sh2,
                                        b22, nullptr, pooled, batch, n, NT);
  k_out<<<G, DIM, 0, stream>>>(pooled, cnt, linW, linb, (float*)d_out);
}